// Round 7
// baseline (195.795 us; speedup 1.0000x reference)
//
#include <hip/hip_runtime.h>
#include <math.h>

#define EPSV 1e-5f

typedef __bf16 bf16;
using bf16x8 = __attribute__((ext_vector_type(8))) __bf16;
using bf16x4 = __attribute__((ext_vector_type(4))) __bf16;
using bf16x2 = __attribute__((ext_vector_type(2))) __bf16;
using f32x4  = __attribute__((ext_vector_type(4))) float;

static __device__ __forceinline__ f32x4 mfma16(bf16x8 a, bf16x8 b, f32x4 c) {
    return __builtin_amdgcn_mfma_f32_16x16x32_bf16(a, b, c, 0, 0, 0);
}
static __device__ __forceinline__ f32x4 zero4() {
    f32x4 z = {0.f, 0.f, 0.f, 0.f};
    return z;
}

// async global->LDS, 16B per lane. LDS dst = wave-uniform base + lane*16.
typedef __attribute__((address_space(1))) const char g_char_t;
typedef __attribute__((address_space(3))) char lds_char_t;
static __device__ __forceinline__ void gll16(const void* g, void* l) {
    __builtin_amdgcn_global_load_lds((g_char_t*)g, (lds_char_t*)l, 16, 0, 0);
}

// exact-GELU via Abramowitz-Stegun 7.1.26 erf (|err| <= 1.5e-7)
static __device__ __forceinline__ float gelu_f(float v) {
    float z = fabsf(v) * 0.70710678118f;
    float t = __builtin_amdgcn_rcpf(1.f + 0.3275911f * z);
    float poly = t * (0.254829592f + t * (-0.284496736f + t * (1.421413741f +
                 t * (-1.453152027f + t * 1.061405429f))));
    float e = __expf(-z * z);
    float erfv = copysignf(1.f - poly * e, v);
    return 0.5f * v * (1.f + erfv);
}

// ---------------------------------------------------------------------------
// Weight prep: conv3x3 fp32 [cout][CIN][3][3] -> bf16 fragment-major
// wt[(((kgt*(CIN/32)+cci)*4+lg)*64 + cout)*8 + j], ci = cci*32+lg*8+j.
// ---------------------------------------------------------------------------
template<int CIN>
__global__ __launch_bounds__(256) void prep_conv_w(const float* __restrict__ w,
                                                   bf16* __restrict__ wt)
{
    int t = blockIdx.x * 256 + threadIdx.x;      // cout*CIN + ci
    if (t >= 64 * CIN) return;
    int cout = t / CIN, ci = t - cout * CIN;
    int cci = ci >> 5, lg = (ci >> 3) & 3, j = ci & 7;
#pragma unroll
    for (int kgt = 0; kgt < 9; ++kgt) {
        float v = w[(size_t)t * 9 + kgt];
        wt[((((size_t)kgt * (CIN >> 5) + cci) * 4 + lg) * 64 + cout) * 8 + j] = (bf16)v;
    }
}

// gc_w fp32 [128][128] -> wt[(((ks*4+lg)*128)+cout)*8+j]
__global__ __launch_bounds__(256) void prep_1x1_w(const float* __restrict__ w,
                                                  bf16* __restrict__ wt)
{
    int t = blockIdx.x * 256 + threadIdx.x;      // cout*128+ci, 16384
    int cout = t >> 7, ci = t & 127;
    int ks = ci >> 5, lg = (ci >> 3) & 3, j = ci & 7;
    wt[(((size_t)(ks * 4 + lg) * 128) + cout) * 8 + j] = (bf16)w[t];
}

// ---------------------------------------------------------------------------
// x fp32 NCHW -> bf16 NHWC; also zeroes the 1KB OOB-source scratch region.
// ---------------------------------------------------------------------------
__global__ __launch_bounds__(256) void cvt_x_nhwc(const float* __restrict__ x,
                                                  bf16* __restrict__ xb,
                                                  float* __restrict__ zb)
{
    __shared__ float t_lds[64 * 68];
    const int bx = blockIdx.x;          // y = bx>>1, half = bx&1
    const int b  = blockIdx.y;
    const int y  = bx >> 1, x0 = (bx & 1) * 64;
    const int tid = threadIdx.x;

    if (bx == 0 && b == 0 && tid < 64)
        ((float4*)zb)[tid] = make_float4(0.f, 0.f, 0.f, 0.f);

    for (int f = tid; f < 64 * 16; f += 256) {
        int c = f >> 4, xu = f & 15;
        float4 v = *(const float4*)&x[((size_t)(b * 64 + c) << 14) + (y << 7) + x0 + xu * 4];
        t_lds[(xu * 4 + 0) * 68 + c] = v.x;
        t_lds[(xu * 4 + 1) * 68 + c] = v.y;
        t_lds[(xu * 4 + 2) * 68 + c] = v.z;
        t_lds[(xu * 4 + 3) * 68 + c] = v.w;
    }
    __syncthreads();
    for (int f = tid; f < 64 * 8; f += 256) {
        int xx = f >> 3, cu = f & 7;
        const float* p = &t_lds[xx * 68 + cu * 8];
        bf16x8 v;
#pragma unroll
        for (int j = 0; j < 8; ++j) v[j] = (bf16)p[j];
        *(bf16x8*)&xb[((size_t)((b * 128 + y) * 128) + x0 + xx) * 64 + cu * 8] = v;
    }
}

// ---------------------------------------------------------------------------
// conv3x3 MFMA implicit GEMM v6.
// Block = 512 thr = 8 waves; wave = one y-row, tile = 8 rows x 64 px.
// Wave tile 64 cout x 64 px (mi=4, nj=4). Halo 10x66 px x 32 ci, SINGLE
// 43KB LDS buffer staged via global_load_lds(16B); vmcnt(0)+2 barriers per
// ci-chunk; 2 blocks/CU x 8 waves = 16 waves (VGPR-capped) hide the drain.
// OUTMODE 0: bf16 NHWC + BN, coalesced via LDS-staged store (2 passes).
// OUTMODE 1: fp32 NCHW + BN + residual(bf16 NHWC).
// ---------------------------------------------------------------------------
template<int CIN, int OUTMODE>
__global__ __launch_bounds__(512) void conv3x3_mfma(
    const bf16* __restrict__ in, const bf16* __restrict__ wt,
    const float* __restrict__ bias,
    const float* __restrict__ bg, const float* __restrict__ bb,
    const float* __restrict__ bm, const float* __restrict__ bv,
    const bf16* __restrict__ resid, const bf16* __restrict__ zb,
    void* __restrict__ outp)
{
    constexpr int NC = CIN >> 5;
    __shared__ bf16 lds_buf[672 * 32];        // 43,008 B (672 = pad of 660 px)

    const int wg = blockIdx.x;                // 512 blocks
    const int v  = (wg & 7) * 64 + (wg >> 3); // bijective XCD chunking
    const int tile = v & 31, b = v >> 5;
    const int x0 = (tile & 1) * 64;
    const int y0 = (tile >> 1) * 8;
    const int tid  = threadIdx.x;
    const int wid  = tid >> 6;
    const int lane = tid & 63;
    const int lix  = lane & 15, lg = lane >> 4;

    // staging: 42 wave-chunks of 64 lanes x 16B; wave w owns {w, w+8, ...}
    int goff[6]; bool gok[6];
#pragma unroll
    for (int i = 0; i < 6; ++i) {
        int chunk = wid + 8 * i;
        int f = chunk * 64 + lane;
        int pix = f >> 2, u = f & 3;
        int iy = pix / 66, ix = pix - iy * 66;
        int gy = y0 + iy - 1, gx = x0 + ix - 1;
        gok[i]  = (chunk < 42) && (pix < 660) &&
                  (unsigned)gy < 128u && (unsigned)gx < 128u;
        goff[i] = ((b * 128 + gy) * 128 + gx) * CIN + u * 8;
    }
    // read bases (elements): pixel p -> p*32 + lg*8; nj adds 512
    int rd[9];
#pragma unroll
    for (int kg = 0; kg < 3; ++kg)
#pragma unroll
        for (int t = 0; t < 3; ++t)
            rd[kg * 3 + t] = ((wid + kg) * 66 + lix + t) * 32 + lg * 8;

    f32x4 acc[4][4];
#pragma unroll
    for (int i = 0; i < 4; ++i)
#pragma unroll
        for (int j = 0; j < 4; ++j) acc[i][j] = zero4();

    auto issue = [&](int cci) {
#pragma unroll
        for (int i = 0; i < 6; ++i) {
            int chunk = wid + 8 * i;
            if (chunk < 42) {
                const void* src = gok[i] ? (const void*)(in + goff[i] + cci * 32)
                                         : (const void*)zb;
                gll16(src, (char*)lds_buf + chunk * 1024);
            }
        }
    };
    auto compute = [&](int cci) {
#pragma unroll
        for (int kgt = 0; kgt < 9; ++kgt) {
            bf16x8 af[4];
            const bf16* wp = wt + ((((size_t)kgt * NC + cci) * 4 + lg) * 64) * 8;
#pragma unroll
            for (int mi = 0; mi < 4; ++mi)
                af[mi] = *(const bf16x8*)&wp[(mi * 16 + lix) * 8];
#pragma unroll
            for (int nj = 0; nj < 4; ++nj) {
                bf16x8 bfr = *(const bf16x8*)&lds_buf[rd[kgt] + nj * 512];
#pragma unroll
                for (int mi = 0; mi < 4; ++mi)
                    acc[mi][nj] = mfma16(af[mi], bfr, acc[mi][nj]);
            }
        }
    };

    issue(0);
#pragma unroll 1
    for (int c = 0; c < NC; ++c) {
        asm volatile("s_waitcnt vmcnt(0)" ::: "memory");
        __syncthreads();
        compute(c);
        if (c + 1 < NC) {
            __syncthreads();
            issue(c + 1);
        }
    }

    if (OUTMODE == 0) {
        // coalesced store via LDS transpose: two passes of 4 rows
        bf16* out = (bf16*)outp;
        bf16* stg = lds_buf;                   // [4*64 px][68] view, 34,816 B
#pragma unroll 1
        for (int p = 0; p < 2; ++p) {
            __syncthreads();
            if ((wid >> 2) == p) {
                int rl = wid & 3;
#pragma unroll
                for (int mi = 0; mi < 4; ++mi) {
                    float A[4], Bc[4];
#pragma unroll
                    for (int r = 0; r < 4; ++r) {
                        int c = mi * 16 + lg * 4 + r;
                        float s = bg[c] * rsqrtf(bv[c] + EPSV);
                        A[r]  = s;
                        Bc[r] = bias[c] * s + bb[c] - bm[c] * s;
                    }
#pragma unroll
                    for (int nj = 0; nj < 4; ++nj) {
                        int px = nj * 16 + lix;
                        bf16x4 vv;
#pragma unroll
                        for (int r = 0; r < 4; ++r)
                            vv[r] = (bf16)(acc[mi][nj][r] * A[r] + Bc[r]);
                        *(bf16x4*)&stg[(rl * 64 + px) * 68 + mi * 16 + lg * 4] = vv;
                    }
                }
            }
            __syncthreads();
#pragma unroll
            for (int k = 0; k < 4; ++k) {
                int idx = k * 512 + tid;       // 2048 16B-units
                int row = idx >> 9, rem = idx & 511;
                int px = rem >> 3, cu = rem & 7;
                bf16x8 vv = *(const bf16x8*)&stg[(row * 64 + px) * 68 + cu * 8];
                *(bf16x8*)&out[((size_t)((b * 128 + y0 + p * 4 + row) * 128)
                                + x0 + px) * 64 + cu * 8] = vv;
            }
        }
    } else {
        float* out = (float*)outp;
        const int gy = y0 + wid;
#pragma unroll
        for (int mi = 0; mi < 4; ++mi) {
            float A[4], Bc[4];
#pragma unroll
            for (int r = 0; r < 4; ++r) {
                int c = mi * 16 + lg * 4 + r;
                float s = bg[c] * rsqrtf(bv[c] + EPSV);
                A[r]  = s;
                Bc[r] = bias[c] * s + bb[c] - bm[c] * s;
            }
#pragma unroll
            for (int nj = 0; nj < 4; ++nj) {
                int px = x0 + nj * 16 + lix;
                bf16x4 rv = *(const bf16x4*)&resid[((size_t)((b * 128 + gy) * 128) + px) * 64
                                                   + mi * 16 + lg * 4];
#pragma unroll
                for (int r = 0; r < 4; ++r) {
                    int c = mi * 16 + lg * 4 + r;
                    size_t oi = ((size_t)(b * 64 + c) << 14) + (gy << 7) + px;
                    out[oi] = acc[mi][nj][r] * A[r] + Bc[r] + (float)rv[r];
                }
            }
        }
    }
}

// ---------------------------------------------------------------------------
// q[b][n][c] = h[b][4*(n/32)][4*(n%32)][c]
// ---------------------------------------------------------------------------
__global__ __launch_bounds__(256) void gather_q(const bf16* __restrict__ h,
                                                bf16* __restrict__ q)
{
    int t = blockIdx.x * 256 + threadIdx.x;   // < 16*1024*8
    int cu = t & 7, n = (t >> 3) & 1023, b = t >> 13;
    int y = (n >> 5) << 2, x = (n & 31) << 2;
    bf16x8 v = *(const bf16x8*)&h[((size_t)((b * 128 + y) * 128 + x)) * 64 + cu * 8];
    *(bf16x8*)&q[((size_t)(b * 1024 + n)) * 64 + cu * 8] = v;
}

// ---------------------------------------------------------------------------
// Fused flash attention (unchanged).
// ---------------------------------------------------------------------------
__global__ __launch_bounds__(256) void attn_fused(const bf16* __restrict__ q,
                                                  bf16* __restrict__ o)
{
    __shared__ bf16 qn[64 * 72];
    __shared__ bf16 kn[128 * 72];
    __shared__ bf16 vt[64 * 136];
    __shared__ bf16 pl[4][16 * 136];
    __shared__ __align__(16) float fac[4][16];
    const int n0 = blockIdx.x * 64, b = blockIdx.y;
    const int tid = threadIdx.x, w = tid >> 6, lane = tid & 63;
    const int lix = lane & 15, lg = lane >> 4;
    const bf16* qb = q + ((size_t)b << 16);

    for (int f = tid; f < 512; f += 256) {
        int row = f >> 3, cu = f & 7;
        *(bf16x8*)&qn[row * 72 + cu * 8] =
            *(const bf16x8*)&qb[(size_t)(n0 + row) * 64 + cu * 8];
    }

    float m_run = -3.0e38f, l_run = 0.f;
    f32x4 oacc[4];
#pragma unroll
    for (int ct = 0; ct < 4; ++ct) oacc[ct] = zero4();

    for (int mt = 0; mt < 1024; mt += 128) {
        __syncthreads();
        for (int f = tid; f < 1024; f += 256) {
            int row = f >> 3, cu = f & 7;
            *(bf16x8*)&kn[row * 72 + cu * 8] =
                *(const bf16x8*)&qb[(size_t)(mt + row) * 64 + cu * 8];
        }
        for (int f = tid; f < 512; f += 256) {
            int mp = f >> 3, cu = f & 7;
            int m = mp * 2;
            bf16x8 a = *(const bf16x8*)&qb[(size_t)(mt + m) * 64 + cu * 8];
            bf16x8 c = *(const bf16x8*)&qb[(size_t)(mt + m + 1) * 64 + cu * 8];
#pragma unroll
            for (int j = 0; j < 8; ++j) {
                bf16x2 pr = {a[j], c[j]};
                *(bf16x2*)&vt[(cu * 8 + j) * 136 + m] = pr;
            }
        }
        __syncthreads();

        bf16x8 bq0 = *(const bf16x8*)&qn[(w * 16 + lix) * 72 + lg * 8];
        bf16x8 bq1 = *(const bf16x8*)&qn[(w * 16 + lix) * 72 + 32 + lg * 8];

        f32x4 s[8];
#pragma unroll
        for (int t = 0; t < 8; ++t) {
            bf16x8 a0 = *(const bf16x8*)&kn[(t * 16 + lix) * 72 + lg * 8];
            bf16x8 a1 = *(const bf16x8*)&kn[(t * 16 + lix) * 72 + 32 + lg * 8];
            s[t] = mfma16(a0, bq0, zero4());
            s[t] = mfma16(a1, bq1, s[t]);
        }

        float mx = -3.0e38f;
#pragma unroll
        for (int t = 0; t < 8; ++t)
#pragma unroll
            for (int r = 0; r < 4; ++r) { s[t][r] *= 0.125f; mx = fmaxf(mx, s[t][r]); }
        mx = fmaxf(mx, __shfl_xor(mx, 16));
        mx = fmaxf(mx, __shfl_xor(mx, 32));
        float m_new = fmaxf(m_run, mx);
        float alpha = __expf(m_run - m_new);

        float psum = 0.f;
#pragma unroll
        for (int t = 0; t < 8; ++t) {
            float p0 = __expf(s[t][0] - m_new), p1 = __expf(s[t][1] - m_new);
            float p2 = __expf(s[t][2] - m_new), p3 = __expf(s[t][3] - m_new);
            psum += (p0 + p1) + (p2 + p3);
            bf16x2 v01 = {(bf16)p0, (bf16)p1};
            bf16x2 v23 = {(bf16)p2, (bf16)p3};
            *(bf16x2*)&pl[w][lix * 136 + t * 16 + lg * 4]     = v01;
            *(bf16x2*)&pl[w][lix * 136 + t * 16 + lg * 4 + 2] = v23;
        }
        psum += __shfl_xor(psum, 16);
        psum += __shfl_xor(psum, 32);
        l_run = l_run * alpha + psum;
        m_run = m_new;
        if (lg == 0) fac[w][lix] = alpha;

        float4 a4 = *(const float4*)&fac[w][lg * 4];
        float aa[4] = {a4.x, a4.y, a4.z, a4.w};
#pragma unroll
        for (int ct = 0; ct < 4; ++ct)
#pragma unroll
            for (int r = 0; r < 4; ++r) oacc[ct][r] *= aa[r];

#pragma unroll
        for (int kk = 0; kk < 4; ++kk) {
            bf16x8 pa = *(const bf16x8*)&pl[w][lix * 136 + kk * 32 + lg * 8];
#pragma unroll
            for (int ct = 0; ct < 4; ++ct) {
                bf16x8 bv = *(const bf16x8*)&vt[(ct * 16 + lix) * 136 + kk * 32 + lg * 8];
                oacc[ct] = mfma16(pa, bv, oacc[ct]);
            }
        }
    }

    if (lg == 0) fac[w][lix] = l_run;
    float4 l4 = *(const float4*)&fac[w][lg * 4];
    float ll[4] = {1.f / l4.x, 1.f / l4.y, 1.f / l4.z, 1.f / l4.w};
#pragma unroll
    for (int ct = 0; ct < 4; ++ct)
#pragma unroll
        for (int r = 0; r < 4; ++r) {
            int n = n0 + w * 16 + lg * 4 + r;
            int c = ct * 16 + lix;
            o[((size_t)(b * 1024 + n)) * 64 + c] = (bf16)(oacc[ct][r] * ll[r]);
        }
}

// ---------------------------------------------------------------------------
// conv1x1 (128->128) + BN + fast exact GELU; coalesced store via LDS.
// ---------------------------------------------------------------------------
__global__ __launch_bounds__(256) void conv1x1_mfma(
    const bf16* __restrict__ h, const bf16* __restrict__ ov,
    const bf16* __restrict__ wt, const float* __restrict__ bias,
    const float* __restrict__ bg, const float* __restrict__ bb,
    const float* __restrict__ bm, const float* __restrict__ bv,
    bf16* __restrict__ g)
{
    __shared__ bf16 in1[128 * 136];           // 34,816 B (reused as out-stage)
    const int y = blockIdx.x, b = blockIdx.y;
    const int tid = threadIdx.x;
    const int wid = tid >> 6, lane = tid & 63;
    const int lix = lane & 15, lg = lane >> 4;
    const int wm = wid >> 1, wn = wid & 1;

    for (int f = tid; f < 128 * 16; f += 256) {
        int px = f >> 4, cu = f & 15;
        bf16x8 v;
        if (cu < 8) {
            v = *(const bf16x8*)&h[((size_t)((b * 128 + y) * 128 + px)) * 64 + cu * 8];
        } else {
            int n = ((y >> 2) << 5) + (px >> 2);
            v = *(const bf16x8*)&ov[((size_t)(b * 1024 + n)) * 64 + (cu - 8) * 8];
        }
        *(bf16x8*)&in1[px * 136 + cu * 8] = v;
    }
    __syncthreads();

    f32x4 acc[4][4];
#pragma unroll
    for (int i = 0; i < 4; ++i)
#pragma unroll
        for (int j = 0; j < 4; ++j) acc[i][j] = zero4();

#pragma unroll
    for (int ks = 0; ks < 4; ++ks) {
        bf16x8 af[4], bfv[4];
#pragma unroll
        for (int mi = 0; mi < 4; ++mi)
            af[mi] = *(const bf16x8*)&wt[(((size_t)(ks * 4 + lg) * 128) + wm * 64 + mi * 16 + lix) * 8];
#pragma unroll
        for (int nj = 0; nj < 4; ++nj)
            bfv[nj] = *(const bf16x8*)&in1[(wn * 64 + nj * 16 + lix) * 136 + ks * 32 + lg * 8];
#pragma unroll
        for (int mi = 0; mi < 4; ++mi)
#pragma unroll
            for (int nj = 0; nj < 4; ++nj)
                acc[mi][nj] = mfma16(af[mi], bfv[nj], acc[mi][nj]);
    }

    __syncthreads();                           // done reading in1
    bf16* stg = in1;                           // [128 px][132] view
#pragma unroll
    for (int mi = 0; mi < 4; ++mi) {
        float A[4], Bc[4];
#pragma unroll
        for (int r = 0; r < 4; ++r) {
            int c = wm * 64 + mi * 16 + lg * 4 + r;
            float s = bg[c] * rsqrtf(bv[c] + EPSV);
            A[r]  = s;
            Bc[r] = bias[c] * s + bb[c] - bm[c] * s;
        }
#pragma unroll
        for (int nj = 0; nj < 4; ++nj) {
            int px = wn * 64 + nj * 16 + lix;
            bf16x4 vv;
#pragma unroll
            for (int r = 0; r < 4; ++r)
                vv[r] = (bf16)gelu_f(acc[mi][nj][r] * A[r] + Bc[r]);
            *(bf16x4*)&stg[px * 132 + wm * 64 + mi * 16 + lg * 4] = vv;
        }
    }
    __syncthreads();
#pragma unroll
    for (int k = 0; k < 8; ++k) {
        int idx = k * 256 + tid;               // 2048 16B-units
        int px = idx >> 4, cu = idx & 15;
        bf16x8 v = *(const bf16x8*)&stg[px * 132 + cu * 8];
        *(bf16x8*)&g[((size_t)((b * 128 + y) * 128) + px) * 128 + cu * 8] = v;
    }
}

// ---------------------------------------------------------------------------
extern "C" void kernel_launch(void* const* d_in, const int* in_sizes, int n_in,
                              void* d_out, int out_size, void* d_ws, size_t ws_size,
                              hipStream_t stream)
{
    const float* x     = (const float*)d_in[0];
    const float* fc1_w = (const float*)d_in[1];
    const float* fc1_b = (const float*)d_in[2];
    const float* bn1_g = (const float*)d_in[3];
    const float* bn1_b = (const float*)d_in[4];
    const float* bn1_m = (const float*)d_in[5];
    const float* bn1_v = (const float*)d_in[6];
    const float* gc_w  = (const float*)d_in[7];
    const float* gc_b  = (const float*)d_in[8];
    const float* bng_g = (const float*)d_in[9];
    const float* bng_b = (const float*)d_in[10];
    const float* bng_m = (const float*)d_in[11];
    const float* bng_v = (const float*)d_in[12];
    const float* fc2_w = (const float*)d_in[13];
    const float* fc2_b = (const float*)d_in[14];
    const float* bn2_g = (const float*)d_in[15];
    const float* bn2_b = (const float*)d_in[16];
    const float* bn2_m = (const float*)d_in[17];
    const float* bn2_v = (const float*)d_in[18];

    char* wsb = (char*)d_ws;
    bf16* x_bf = (bf16*)wsb;                      // 33,554,432 B
    bf16* h    = (bf16*)(wsb + 33554432);         // 33,554,432 B
    bf16* g    = (bf16*)(wsb + 67108864);         // 67,108,864 B
    bf16* q    = (bf16*)(wsb + 134217728);        //  2,097,152 B
    bf16* o    = (bf16*)(wsb + 136314880);        //  2,097,152 B
    bf16* wt1  = (bf16*)(wsb + 138412032);        //     73,728 B
    bf16* wt2  = (bf16*)(wsb + 138485760);        //    147,456 B
    bf16* wtg  = (bf16*)(wsb + 138633216);        //     32,768 B
    bf16* zb   = (bf16*)(wsb + 138665984);        //      1,024 B

    prep_conv_w<64><<<16, 256, 0, stream>>>(fc1_w, wt1);
    prep_conv_w<128><<<32, 256, 0, stream>>>(fc2_w, wt2);
    prep_1x1_w<<<64, 256, 0, stream>>>(gc_w, wtg);

    cvt_x_nhwc<<<dim3(256, 16), 256, 0, stream>>>(x, x_bf, (float*)zb);

    conv3x3_mfma<64, 0><<<512, 512, 0, stream>>>(
        x_bf, wt1, fc1_b, bn1_g, bn1_b, bn1_m, bn1_v, nullptr, zb, h);

    gather_q<<<512, 256, 0, stream>>>(h, q);

    attn_fused<<<dim3(16, 16), 256, 0, stream>>>(q, o);

    conv1x1_mfma<<<dim3(128, 16), 256, 0, stream>>>(
        h, o, wtg, gc_b, bng_g, bng_b, bng_m, bng_v, g);

    conv3x3_mfma<128, 1><<<512, 512, 0, stream>>>(
        g, wt2, fc2_b, bn2_g, bn2_b, bn2_m, bn2_v, x_bf, zb, (float*)d_out);
}

// Round 8
// 189.242 us; speedup vs baseline: 1.0346x; 1.0346x over previous
//
#include <hip/hip_runtime.h>
#include <math.h>

#define EPSV 1e-5f

typedef __bf16 bf16;
using bf16x8 = __attribute__((ext_vector_type(8))) __bf16;
using bf16x4 = __attribute__((ext_vector_type(4))) __bf16;
using bf16x2 = __attribute__((ext_vector_type(2))) __bf16;
using f32x4  = __attribute__((ext_vector_type(4))) float;

static __device__ __forceinline__ f32x4 mfma16(bf16x8 a, bf16x8 b, f32x4 c) {
    return __builtin_amdgcn_mfma_f32_16x16x32_bf16(a, b, c, 0, 0, 0);
}
static __device__ __forceinline__ f32x4 zero4() {
    f32x4 z = {0.f, 0.f, 0.f, 0.f};
    return z;
}

// async global->LDS, 16B per lane. LDS dst = wave-uniform base + lane*16;
// global src is per-lane.
typedef __attribute__((address_space(1))) const char g_char_t;
typedef __attribute__((address_space(3))) char lds_char_t;
static __device__ __forceinline__ void gll16(const void* g, void* l) {
    __builtin_amdgcn_global_load_lds((g_char_t*)g, (lds_char_t*)l, 16, 0, 0);
}

// exact-GELU via Abramowitz-Stegun 7.1.26 erf (|err| <= 1.5e-7)
static __device__ __forceinline__ float gelu_f(float v) {
    float z = fabsf(v) * 0.70710678118f;
    float t = __builtin_amdgcn_rcpf(1.f + 0.3275911f * z);
    float poly = t * (0.254829592f + t * (-0.284496736f + t * (1.421413741f +
                 t * (-1.453152027f + t * 1.061405429f))));
    float e = __expf(-z * z);
    float erfv = copysignf(1.f - poly * e, v);
    return 0.5f * v * (1.f + erfv);
}

// ---------------------------------------------------------------------------
// Weight prep: conv3x3 fp32 [cout][CIN][3][3] -> bf16 LANE-LINEAR fragments:
// wt[(((kgt*NC+cci)*4 + mi)*64 + lane)*8 + j] where lane = lg*16+lix,
// cout = mi*16+lix, ci = cci*32+lg*8+j. A wave's (kgt,mi) fragment is a
// contiguous 1KB block readable at base+lane*16 (gll16- and LDS-linear).
// ---------------------------------------------------------------------------
template<int CIN>
__global__ __launch_bounds__(256) void prep_conv_w(const float* __restrict__ w,
                                                   bf16* __restrict__ wt)
{
    int t = blockIdx.x * 256 + threadIdx.x;      // cout*CIN + ci
    if (t >= 64 * CIN) return;
    int cout = t / CIN, ci = t - cout * CIN;
    int cci = ci >> 5, lg = (ci >> 3) & 3, j = ci & 7;
    int mi = cout >> 4, lix = cout & 15;
#pragma unroll
    for (int kgt = 0; kgt < 9; ++kgt) {
        float v = w[(size_t)t * 9 + kgt];
        wt[((((size_t)kgt * (CIN >> 5) + cci) * 4 + mi) * 64 + lg * 16 + lix) * 8 + j]
            = (bf16)v;
    }
}

// gc_w fp32 [128][128] -> wt[(((ks*4+lg)*128)+cout)*8+j]
__global__ __launch_bounds__(256) void prep_1x1_w(const float* __restrict__ w,
                                                  bf16* __restrict__ wt)
{
    int t = blockIdx.x * 256 + threadIdx.x;      // cout*128+ci, 16384
    int cout = t >> 7, ci = t & 127;
    int ks = ci >> 5, lg = (ci >> 3) & 3, j = ci & 7;
    wt[(((size_t)(ks * 4 + lg) * 128) + cout) * 8 + j] = (bf16)w[t];
}

// ---------------------------------------------------------------------------
// x fp32 NCHW -> bf16 NHWC; also zeroes the 1KB OOB-source scratch region.
// ---------------------------------------------------------------------------
__global__ __launch_bounds__(256) void cvt_x_nhwc(const float* __restrict__ x,
                                                  bf16* __restrict__ xb,
                                                  float* __restrict__ zb)
{
    __shared__ float t_lds[64 * 68];
    const int bx = blockIdx.x;          // y = bx>>1, half = bx&1
    const int b  = blockIdx.y;
    const int y  = bx >> 1, x0 = (bx & 1) * 64;
    const int tid = threadIdx.x;

    if (bx == 0 && b == 0 && tid < 64)
        ((float4*)zb)[tid] = make_float4(0.f, 0.f, 0.f, 0.f);

    for (int f = tid; f < 64 * 16; f += 256) {
        int c = f >> 4, xu = f & 15;
        float4 v = *(const float4*)&x[((size_t)(b * 64 + c) << 14) + (y << 7) + x0 + xu * 4];
        t_lds[(xu * 4 + 0) * 68 + c] = v.x;
        t_lds[(xu * 4 + 1) * 68 + c] = v.y;
        t_lds[(xu * 4 + 2) * 68 + c] = v.z;
        t_lds[(xu * 4 + 3) * 68 + c] = v.w;
    }
    __syncthreads();
    for (int f = tid; f < 64 * 8; f += 256) {
        int xx = f >> 3, cu = f & 7;
        const float* p = &t_lds[xx * 68 + cu * 8];
        bf16x8 v;
#pragma unroll
        for (int j = 0; j < 8; ++j) v[j] = (bf16)p[j];
        *(bf16x8*)&xb[((size_t)((b * 128 + y) * 128) + x0 + xx) * 64 + cu * 8] = v;
    }
}

// ---------------------------------------------------------------------------
// conv3x3 MFMA implicit GEMM v7.
// Block = 512 thr = 8 waves; wave = one y-row, tile = 8 rows x 64 px.
// Wave tile 64 cout x 64 px (mi=4, nj=4). NEW vs v6: weights staged in LDS
// ONCE PER BLOCK per ci-chunk (lane-linear layout, gll16) instead of each
// wave streaming 36KB from L2 -> 8x less L2 weight traffic, conflict-free
// linear af reads. LDS: input 42KB + weights 36KB = 78KB -> 2 blocks/CU.
// OUTMODE 0: bf16 NHWC + BN, coalesced via LDS-staged store (2 passes).
// OUTMODE 1: fp32 NCHW + BN + residual(bf16 NHWC).
// ---------------------------------------------------------------------------
template<int CIN, int OUTMODE>
__global__ __launch_bounds__(512) void conv3x3_mfma(
    const bf16* __restrict__ in, const bf16* __restrict__ wt,
    const float* __restrict__ bias,
    const float* __restrict__ bg, const float* __restrict__ bb,
    const float* __restrict__ bm, const float* __restrict__ bv,
    const bf16* __restrict__ resid, const bf16* __restrict__ zb,
    void* __restrict__ outp)
{
    constexpr int NC = CIN >> 5;
    __shared__ bf16 in_lds[672 * 32];         // 43,008 B
    __shared__ bf16 w_lds[36 * 512];          // 36,864 B (9 kgt x 4 mi x 1KB)

    const int wg = blockIdx.x;                // 512 blocks
    const int v  = (wg & 7) * 64 + (wg >> 3); // bijective XCD chunking
    const int tile = v & 31, b = v >> 5;
    const int x0 = (tile & 1) * 64;
    const int y0 = (tile >> 1) * 8;
    const int tid  = threadIdx.x;
    const int wid  = tid >> 6;
    const int lane = tid & 63;
    const int lix  = lane & 15, lg = lane >> 4;

    // input staging: 42 wave-chunks of 64 lanes x 16B; wave w owns {w, w+8,..}
    int goff[6]; bool gok[6];
#pragma unroll
    for (int i = 0; i < 6; ++i) {
        int chunk = wid + 8 * i;
        int f = chunk * 64 + lane;
        int pix = f >> 2, u = f & 3;
        int iy = pix / 66, ix = pix - iy * 66;
        int gy = y0 + iy - 1, gx = x0 + ix - 1;
        gok[i]  = (chunk < 42) && (pix < 660) &&
                  (unsigned)gy < 128u && (unsigned)gx < 128u;
        goff[i] = ((b * 128 + gy) * 128 + gx) * CIN + u * 8;
    }
    // bfr read bases (elements): pixel p -> p*32 + lg*8; nj adds 512
    int rd[9];
#pragma unroll
    for (int kg = 0; kg < 3; ++kg)
#pragma unroll
        for (int t = 0; t < 3; ++t)
            rd[kg * 3 + t] = ((wid + kg) * 66 + lix + t) * 32 + lg * 8;

    f32x4 acc[4][4];
#pragma unroll
    for (int i = 0; i < 4; ++i)
#pragma unroll
        for (int j = 0; j < 4; ++j) acc[i][j] = zero4();

    auto issue_in = [&](int cci) {
#pragma unroll
        for (int i = 0; i < 6; ++i) {
            int chunk = wid + 8 * i;
            if (chunk < 42) {
                const void* src = gok[i] ? (const void*)(in + goff[i] + cci * 32)
                                         : (const void*)zb;
                gll16(src, (char*)in_lds + chunk * 1024);
            }
        }
    };
    auto issue_w = [&](int cci) {
#pragma unroll
        for (int i = 0; i < 5; ++i) {
            int chunk = wid + 8 * i;              // = kgt*4 + mi
            if (chunk < 36) {
                const bf16* src = wt + ((size_t)(chunk >> 2) * NC + cci) * 2048
                                     + (chunk & 3) * 512 + lane * 8;
                gll16(src, (char*)w_lds + chunk * 1024);
            }
        }
    };
    auto compute = [&]() {
#pragma unroll
        for (int kgt = 0; kgt < 9; ++kgt) {
            bf16x8 af[4];
#pragma unroll
            for (int mi = 0; mi < 4; ++mi)
                af[mi] = *(const bf16x8*)&w_lds[(kgt * 4 + mi) * 512 + lane * 8];
#pragma unroll
            for (int nj = 0; nj < 4; ++nj) {
                bf16x8 bfr = *(const bf16x8*)&in_lds[rd[kgt] + nj * 512];
#pragma unroll
                for (int mi = 0; mi < 4; ++mi)
                    acc[mi][nj] = mfma16(af[mi], bfr, acc[mi][nj]);
            }
        }
    };

    issue_in(0);
    issue_w(0);
#pragma unroll 1
    for (int c = 0; c < NC; ++c) {
        asm volatile("s_waitcnt vmcnt(0)" ::: "memory");
        __syncthreads();
        compute();
        if (c + 1 < NC) {
            __syncthreads();
            issue_in(c + 1);
            issue_w(c + 1);
        }
    }

    if (OUTMODE == 0) {
        // coalesced store via LDS transpose: two passes of 4 rows
        bf16* out = (bf16*)outp;
        bf16* stg = in_lds;                    // [4*64 px][68] view, 34,816 B
#pragma unroll 1
        for (int p = 0; p < 2; ++p) {
            __syncthreads();
            if ((wid >> 2) == p) {
                int rl = wid & 3;
#pragma unroll
                for (int mi = 0; mi < 4; ++mi) {
                    float A[4], Bc[4];
#pragma unroll
                    for (int r = 0; r < 4; ++r) {
                        int c = mi * 16 + lg * 4 + r;
                        float s = bg[c] * rsqrtf(bv[c] + EPSV);
                        A[r]  = s;
                        Bc[r] = bias[c] * s + bb[c] - bm[c] * s;
                    }
#pragma unroll
                    for (int nj = 0; nj < 4; ++nj) {
                        int px = nj * 16 + lix;
                        bf16x4 vv;
#pragma unroll
                        for (int r = 0; r < 4; ++r)
                            vv[r] = (bf16)(acc[mi][nj][r] * A[r] + Bc[r]);
                        *(bf16x4*)&stg[(rl * 64 + px) * 68 + mi * 16 + lg * 4] = vv;
                    }
                }
            }
            __syncthreads();
#pragma unroll
            for (int k = 0; k < 4; ++k) {
                int idx = k * 512 + tid;       // 2048 16B-units
                int row = idx >> 9, rem = idx & 511;
                int px = rem >> 3, cu = rem & 7;
                bf16x8 vv = *(const bf16x8*)&stg[(row * 64 + px) * 68 + cu * 8];
                *(bf16x8*)&out[((size_t)((b * 128 + y0 + p * 4 + row) * 128)
                                + x0 + px) * 64 + cu * 8] = vv;
            }
        }
    } else {
        float* out = (float*)outp;
        const int gy = y0 + wid;
#pragma unroll
        for (int mi = 0; mi < 4; ++mi) {
            float A[4], Bc[4];
#pragma unroll
            for (int r = 0; r < 4; ++r) {
                int c = mi * 16 + lg * 4 + r;
                float s = bg[c] * rsqrtf(bv[c] + EPSV);
                A[r]  = s;
                Bc[r] = bias[c] * s + bb[c] - bm[c] * s;
            }
#pragma unroll
            for (int nj = 0; nj < 4; ++nj) {
                int px = x0 + nj * 16 + lix;
                bf16x4 rv = *(const bf16x4*)&resid[((size_t)((b * 128 + gy) * 128) + px) * 64
                                                   + mi * 16 + lg * 4];
#pragma unroll
                for (int r = 0; r < 4; ++r) {
                    int c = mi * 16 + lg * 4 + r;
                    size_t oi = ((size_t)(b * 64 + c) << 14) + (gy << 7) + px;
                    out[oi] = acc[mi][nj][r] * A[r] + Bc[r] + (float)rv[r];
                }
            }
        }
    }
}

// ---------------------------------------------------------------------------
// q[b][n][c] = h[b][4*(n/32)][4*(n%32)][c]
// ---------------------------------------------------------------------------
__global__ __launch_bounds__(256) void gather_q(const bf16* __restrict__ h,
                                                bf16* __restrict__ q)
{
    int t = blockIdx.x * 256 + threadIdx.x;   // < 16*1024*8
    int cu = t & 7, n = (t >> 3) & 1023, b = t >> 13;
    int y = (n >> 5) << 2, x = (n & 31) << 2;
    bf16x8 v = *(const bf16x8*)&h[((size_t)((b * 128 + y) * 128 + x)) * 64 + cu * 8];
    *(bf16x8*)&q[((size_t)(b * 1024 + n)) * 64 + cu * 8] = v;
}

// ---------------------------------------------------------------------------
// Fused flash attention (unchanged).
// ---------------------------------------------------------------------------
__global__ __launch_bounds__(256) void attn_fused(const bf16* __restrict__ q,
                                                  bf16* __restrict__ o)
{
    __shared__ bf16 qn[64 * 72];
    __shared__ bf16 kn[128 * 72];
    __shared__ bf16 vt[64 * 136];
    __shared__ bf16 pl[4][16 * 136];
    __shared__ __align__(16) float fac[4][16];
    const int n0 = blockIdx.x * 64, b = blockIdx.y;
    const int tid = threadIdx.x, w = tid >> 6, lane = tid & 63;
    const int lix = lane & 15, lg = lane >> 4;
    const bf16* qb = q + ((size_t)b << 16);

    for (int f = tid; f < 512; f += 256) {
        int row = f >> 3, cu = f & 7;
        *(bf16x8*)&qn[row * 72 + cu * 8] =
            *(const bf16x8*)&qb[(size_t)(n0 + row) * 64 + cu * 8];
    }

    float m_run = -3.0e38f, l_run = 0.f;
    f32x4 oacc[4];
#pragma unroll
    for (int ct = 0; ct < 4; ++ct) oacc[ct] = zero4();

    for (int mt = 0; mt < 1024; mt += 128) {
        __syncthreads();
        for (int f = tid; f < 1024; f += 256) {
            int row = f >> 3, cu = f & 7;
            *(bf16x8*)&kn[row * 72 + cu * 8] =
                *(const bf16x8*)&qb[(size_t)(mt + row) * 64 + cu * 8];
        }
        for (int f = tid; f < 512; f += 256) {
            int mp = f >> 3, cu = f & 7;
            int m = mp * 2;
            bf16x8 a = *(const bf16x8*)&qb[(size_t)(mt + m) * 64 + cu * 8];
            bf16x8 c = *(const bf16x8*)&qb[(size_t)(mt + m + 1) * 64 + cu * 8];
#pragma unroll
            for (int j = 0; j < 8; ++j) {
                bf16x2 pr = {a[j], c[j]};
                *(bf16x2*)&vt[(cu * 8 + j) * 136 + m] = pr;
            }
        }
        __syncthreads();

        bf16x8 bq0 = *(const bf16x8*)&qn[(w * 16 + lix) * 72 + lg * 8];
        bf16x8 bq1 = *(const bf16x8*)&qn[(w * 16 + lix) * 72 + 32 + lg * 8];

        f32x4 s[8];
#pragma unroll
        for (int t = 0; t < 8; ++t) {
            bf16x8 a0 = *(const bf16x8*)&kn[(t * 16 + lix) * 72 + lg * 8];
            bf16x8 a1 = *(const bf16x8*)&kn[(t * 16 + lix) * 72 + 32 + lg * 8];
            s[t] = mfma16(a0, bq0, zero4());
            s[t] = mfma16(a1, bq1, s[t]);
        }

        float mx = -3.0e38f;
#pragma unroll
        for (int t = 0; t < 8; ++t)
#pragma unroll
            for (int r = 0; r < 4; ++r) { s[t][r] *= 0.125f; mx = fmaxf(mx, s[t][r]); }
        mx = fmaxf(mx, __shfl_xor(mx, 16));
        mx = fmaxf(mx, __shfl_xor(mx, 32));
        float m_new = fmaxf(m_run, mx);
        float alpha = __expf(m_run - m_new);

        float psum = 0.f;
#pragma unroll
        for (int t = 0; t < 8; ++t) {
            float p0 = __expf(s[t][0] - m_new), p1 = __expf(s[t][1] - m_new);
            float p2 = __expf(s[t][2] - m_new), p3 = __expf(s[t][3] - m_new);
            psum += (p0 + p1) + (p2 + p3);
            bf16x2 v01 = {(bf16)p0, (bf16)p1};
            bf16x2 v23 = {(bf16)p2, (bf16)p3};
            *(bf16x2*)&pl[w][lix * 136 + t * 16 + lg * 4]     = v01;
            *(bf16x2*)&pl[w][lix * 136 + t * 16 + lg * 4 + 2] = v23;
        }
        psum += __shfl_xor(psum, 16);
        psum += __shfl_xor(psum, 32);
        l_run = l_run * alpha + psum;
        m_run = m_new;
        if (lg == 0) fac[w][lix] = alpha;

        float4 a4 = *(const float4*)&fac[w][lg * 4];
        float aa[4] = {a4.x, a4.y, a4.z, a4.w};
#pragma unroll
        for (int ct = 0; ct < 4; ++ct)
#pragma unroll
            for (int r = 0; r < 4; ++r) oacc[ct][r] *= aa[r];

#pragma unroll
        for (int kk = 0; kk < 4; ++kk) {
            bf16x8 pa = *(const bf16x8*)&pl[w][lix * 136 + kk * 32 + lg * 8];
#pragma unroll
            for (int ct = 0; ct < 4; ++ct) {
                bf16x8 bv = *(const bf16x8*)&vt[(ct * 16 + lix) * 136 + kk * 32 + lg * 8];
                oacc[ct] = mfma16(pa, bv, oacc[ct]);
            }
        }
    }

    if (lg == 0) fac[w][lix] = l_run;
    float4 l4 = *(const float4*)&fac[w][lg * 4];
    float ll[4] = {1.f / l4.x, 1.f / l4.y, 1.f / l4.z, 1.f / l4.w};
#pragma unroll
    for (int ct = 0; ct < 4; ++ct)
#pragma unroll
        for (int r = 0; r < 4; ++r) {
            int n = n0 + w * 16 + lg * 4 + r;
            int c = ct * 16 + lix;
            o[((size_t)(b * 1024 + n)) * 64 + c] = (bf16)(oacc[ct][r] * ll[r]);
        }
}

// ---------------------------------------------------------------------------
// conv1x1 (128->128) + BN + fast exact GELU; coalesced store via LDS.
// ---------------------------------------------------------------------------
__global__ __launch_bounds__(256) void conv1x1_mfma(
    const bf16* __restrict__ h, const bf16* __restrict__ ov,
    const bf16* __restrict__ wt, const float* __restrict__ bias,
    const float* __restrict__ bg, const float* __restrict__ bb,
    const float* __restrict__ bm, const float* __restrict__ bv,
    bf16* __restrict__ g)
{
    __shared__ bf16 in1[128 * 136];           // 34,816 B (reused as out-stage)
    const int y = blockIdx.x, b = blockIdx.y;
    const int tid = threadIdx.x;
    const int wid = tid >> 6, lane = tid & 63;
    const int lix = lane & 15, lg = lane >> 4;
    const int wm = wid >> 1, wn = wid & 1;

    for (int f = tid; f < 128 * 16; f += 256) {
        int px = f >> 4, cu = f & 15;
        bf16x8 v;
        if (cu < 8) {
            v = *(const bf16x8*)&h[((size_t)((b * 128 + y) * 128 + px)) * 64 + cu * 8];
        } else {
            int n = ((y >> 2) << 5) + (px >> 2);
            v = *(const bf16x8*)&ov[((size_t)(b * 1024 + n)) * 64 + (cu - 8) * 8];
        }
        *(bf16x8*)&in1[px * 136 + cu * 8] = v;
    }
    __syncthreads();

    f32x4 acc[4][4];
#pragma unroll
    for (int i = 0; i < 4; ++i)
#pragma unroll
        for (int j = 0; j < 4; ++j) acc[i][j] = zero4();

#pragma unroll
    for (int ks = 0; ks < 4; ++ks) {
        bf16x8 af[4], bfv[4];
#pragma unroll
        for (int mi = 0; mi < 4; ++mi)
            af[mi] = *(const bf16x8*)&wt[(((size_t)(ks * 4 + lg) * 128) + wm * 64 + mi * 16 + lix) * 8];
#pragma unroll
        for (int nj = 0; nj < 4; ++nj)
            bfv[nj] = *(const bf16x8*)&in1[(wn * 64 + nj * 16 + lix) * 136 + ks * 32 + lg * 8];
#pragma unroll
        for (int mi = 0; mi < 4; ++mi)
#pragma unroll
            for (int nj = 0; nj < 4; ++nj)
                acc[mi][nj] = mfma16(af[mi], bfv[nj], acc[mi][nj]);
    }

    __syncthreads();                           // done reading in1
    bf16* stg = in1;                           // [128 px][132] view
#pragma unroll
    for (int mi = 0; mi < 4; ++mi) {
        float A[4], Bc[4];
#pragma unroll
        for (int r = 0; r < 4; ++r) {
            int c = wm * 64 + mi * 16 + lg * 4 + r;
            float s = bg[c] * rsqrtf(bv[c] + EPSV);
            A[r]  = s;
            Bc[r] = bias[c] * s + bb[c] - bm[c] * s;
        }
#pragma unroll
        for (int nj = 0; nj < 4; ++nj) {
            int px = wn * 64 + nj * 16 + lix;
            bf16x4 vv;
#pragma unroll
            for (int r = 0; r < 4; ++r)
                vv[r] = (bf16)gelu_f(acc[mi][nj][r] * A[r] + Bc[r]);
            *(bf16x4*)&stg[px * 132 + wm * 64 + mi * 16 + lg * 4] = vv;
        }
    }
    __syncthreads();
#pragma unroll
    for (int k = 0; k < 8; ++k) {
        int idx = k * 256 + tid;               // 2048 16B-units
        int px = idx >> 4, cu = idx & 15;
        bf16x8 v = *(const bf16x8*)&stg[px * 132 + cu * 8];
        *(bf16x8*)&g[((size_t)((b * 128 + y) * 128) + px) * 128 + cu * 8] = v;
    }
}

// ---------------------------------------------------------------------------
extern "C" void kernel_launch(void* const* d_in, const int* in_sizes, int n_in,
                              void* d_out, int out_size, void* d_ws, size_t ws_size,
                              hipStream_t stream)
{
    const float* x     = (const float*)d_in[0];
    const float* fc1_w = (const float*)d_in[1];
    const float* fc1_b = (const float*)d_in[2];
    const float* bn1_g = (const float*)d_in[3];
    const float* bn1_b = (const float*)d_in[4];
    const float* bn1_m = (const float*)d_in[5];
    const float* bn1_v = (const float*)d_in[6];
    const float* gc_w  = (const float*)d_in[7];
    const float* gc_b  = (const float*)d_in[8];
    const float* bng_g = (const float*)d_in[9];
    const float* bng_b = (const float*)d_in[10];
    const float* bng_m = (const float*)d_in[11];
    const float* bng_v = (const float*)d_in[12];
    const float* fc2_w = (const float*)d_in[13];
    const float* fc2_b = (const float*)d_in[14];
    const float* bn2_g = (const float*)d_in[15];
    const float* bn2_b = (const float*)d_in[16];
    const float* bn2_m = (const float*)d_in[17];
    const float* bn2_v = (const float*)d_in[18];

    char* wsb = (char*)d_ws;
    bf16* x_bf = (bf16*)wsb;                      // 33,554,432 B
    bf16* h    = (bf16*)(wsb + 33554432);         // 33,554,432 B
    bf16* g    = (bf16*)(wsb + 67108864);         // 67,108,864 B
    bf16* q    = (bf16*)(wsb + 134217728);        //  2,097,152 B
    bf16* o    = (bf16*)(wsb + 136314880);        //  2,097,152 B
    bf16* wt1  = (bf16*)(wsb + 138412032);        //     73,728 B
    bf16* wt2  = (bf16*)(wsb + 138485760);        //    147,456 B
    bf16* wtg  = (bf16*)(wsb + 138633216);        //     32,768 B
    bf16* zb   = (bf16*)(wsb + 138665984);        //      1,024 B

    prep_conv_w<64><<<16, 256, 0, stream>>>(fc1_w, wt1);
    prep_conv_w<128><<<32, 256, 0, stream>>>(fc2_w, wt2);
    prep_1x1_w<<<64, 256, 0, stream>>>(gc_w, wtg);

    cvt_x_nhwc<<<dim3(256, 16), 256, 0, stream>>>(x, x_bf, (float*)zb);

    conv3x3_mfma<64, 0><<<512, 512, 0, stream>>>(
        x_bf, wt1, fc1_b, bn1_g, bn1_b, bn1_m, bn1_v, nullptr, zb, h);

    gather_q<<<512, 256, 0, stream>>>(h, q);

    attn_fused<<<dim3(16, 16), 256, 0, stream>>>(q, o);

    conv1x1_mfma<<<dim3(128, 16), 256, 0, stream>>>(
        h, o, wtg, gc_b, bng_g, bng_b, bng_m, bng_v, g);

    conv3x3_mfma<128, 1><<<512, 512, 0, stream>>>(
        g, wt2, fc2_b, bn2_g, bn2_b, bn2_m, bn2_v, x_bf, zb, (float*)d_out);
}

// Round 9
// 186.684 us; speedup vs baseline: 1.0488x; 1.0137x over previous
//
#include <hip/hip_runtime.h>
#include <math.h>

#define EPSV 1e-5f

typedef __bf16 bf16;
using bf16x8 = __attribute__((ext_vector_type(8))) __bf16;
using bf16x4 = __attribute__((ext_vector_type(4))) __bf16;
using bf16x2 = __attribute__((ext_vector_type(2))) __bf16;
using f32x4  = __attribute__((ext_vector_type(4))) float;

static __device__ __forceinline__ f32x4 mfma16(bf16x8 a, bf16x8 b, f32x4 c) {
    return __builtin_amdgcn_mfma_f32_16x16x32_bf16(a, b, c, 0, 0, 0);
}
static __device__ __forceinline__ f32x4 zero4() {
    f32x4 z = {0.f, 0.f, 0.f, 0.f};
    return z;
}

// async global->LDS, 16B per lane. LDS dst = wave-uniform base + lane*16;
// global src is per-lane.
typedef __attribute__((address_space(1))) const char g_char_t;
typedef __attribute__((address_space(3))) char lds_char_t;
static __device__ __forceinline__ void gll16(const void* g, void* l) {
    __builtin_amdgcn_global_load_lds((g_char_t*)g, (lds_char_t*)l, 16, 0, 0);
}

// exact-GELU via Abramowitz-Stegun 7.1.26 erf (|err| <= 1.5e-7)
static __device__ __forceinline__ float gelu_f(float v) {
    float z = fabsf(v) * 0.70710678118f;
    float t = __builtin_amdgcn_rcpf(1.f + 0.3275911f * z);
    float poly = t * (0.254829592f + t * (-0.284496736f + t * (1.421413741f +
                 t * (-1.453152027f + t * 1.061405429f))));
    float e = __expf(-z * z);
    float erfv = copysignf(1.f - poly * e, v);
    return 0.5f * v * (1.f + erfv);
}

// ---------------------------------------------------------------------------
// Weight prep: conv3x3 fp32 [cout][CIN][3][3] -> bf16 LANE-LINEAR fragments:
// wt[(((kgt*NC+cci)*4 + mi)*64 + lane)*8 + j] where lane = lg*16+lix,
// cout = mi*16+lix, ci = cci*32+lg*8+j. A wave's (kgt,mi) fragment is a
// contiguous 1KB block readable at base+lane*16 (gll16- and LDS-linear).
// ---------------------------------------------------------------------------
template<int CIN>
__global__ __launch_bounds__(256) void prep_conv_w(const float* __restrict__ w,
                                                   bf16* __restrict__ wt)
{
    int t = blockIdx.x * 256 + threadIdx.x;      // cout*CIN + ci
    if (t >= 64 * CIN) return;
    int cout = t / CIN, ci = t - cout * CIN;
    int cci = ci >> 5, lg = (ci >> 3) & 3, j = ci & 7;
    int mi = cout >> 4, lix = cout & 15;
#pragma unroll
    for (int kgt = 0; kgt < 9; ++kgt) {
        float v = w[(size_t)t * 9 + kgt];
        wt[((((size_t)kgt * (CIN >> 5) + cci) * 4 + mi) * 64 + lg * 16 + lix) * 8 + j]
            = (bf16)v;
    }
}

// gc_w fp32 [128][128] -> wt[(((ks*4+lg)*128)+cout)*8+j]
__global__ __launch_bounds__(256) void prep_1x1_w(const float* __restrict__ w,
                                                  bf16* __restrict__ wt)
{
    int t = blockIdx.x * 256 + threadIdx.x;      // cout*128+ci, 16384
    int cout = t >> 7, ci = t & 127;
    int ks = ci >> 5, lg = (ci >> 3) & 3, j = ci & 7;
    wt[(((size_t)(ks * 4 + lg) * 128) + cout) * 8 + j] = (bf16)w[t];
}

// ---------------------------------------------------------------------------
// x fp32 NCHW -> bf16 NHWC; also zeroes the 1KB OOB-source scratch region.
// ---------------------------------------------------------------------------
__global__ __launch_bounds__(256) void cvt_x_nhwc(const float* __restrict__ x,
                                                  bf16* __restrict__ xb,
                                                  float* __restrict__ zb)
{
    __shared__ float t_lds[64 * 68];
    const int bx = blockIdx.x;          // y = bx>>1, half = bx&1
    const int b  = blockIdx.y;
    const int y  = bx >> 1, x0 = (bx & 1) * 64;
    const int tid = threadIdx.x;

    if (bx == 0 && b == 0 && tid < 64)
        ((float4*)zb)[tid] = make_float4(0.f, 0.f, 0.f, 0.f);

    for (int f = tid; f < 64 * 16; f += 256) {
        int c = f >> 4, xu = f & 15;
        float4 v = *(const float4*)&x[((size_t)(b * 64 + c) << 14) + (y << 7) + x0 + xu * 4];
        t_lds[(xu * 4 + 0) * 68 + c] = v.x;
        t_lds[(xu * 4 + 1) * 68 + c] = v.y;
        t_lds[(xu * 4 + 2) * 68 + c] = v.z;
        t_lds[(xu * 4 + 3) * 68 + c] = v.w;
    }
    __syncthreads();
    for (int f = tid; f < 64 * 8; f += 256) {
        int xx = f >> 3, cu = f & 7;
        const float* p = &t_lds[xx * 68 + cu * 8];
        bf16x8 v;
#pragma unroll
        for (int j = 0; j < 8; ++j) v[j] = (bf16)p[j];
        *(bf16x8*)&xb[((size_t)((b * 128 + y) * 128) + x0 + xx) * 64 + cu * 8] = v;
    }
}

// ---------------------------------------------------------------------------
// conv3x3 MFMA implicit GEMM v8: software-pipelined.
// Block = 512 thr = 8 waves; wave = one y-row, tile = 8 rows x 64 px,
// wave tile 64 cout x 64 px (mi=4, nj=4).
// Input AND weights double-buffered in LDS (43KB*2 + 36KB*2 = 156KB,
// 1 block/CU), staged via global_load_lds. RAW s_barrier + counted vmcnt:
// chunk c+1's loads stay in flight across the barrier while chunk c
// computes (HIP __syncthreads would drain vmcnt(0) - defeats the pipe).
// OUTMODE 0: bf16 NHWC + BN, coalesced single-pass LDS-staged store.
// OUTMODE 1: fp32 NCHW + BN + residual(bf16 NHWC).
// ---------------------------------------------------------------------------
template<int CIN, int OUTMODE>
__global__ __launch_bounds__(512) void conv3x3_mfma(
    const bf16* __restrict__ in, const bf16* __restrict__ wt,
    const float* __restrict__ bias,
    const float* __restrict__ bg, const float* __restrict__ bb,
    const float* __restrict__ bm, const float* __restrict__ bv,
    const bf16* __restrict__ resid, const bf16* __restrict__ zb,
    void* __restrict__ outp)
{
    constexpr int NC = CIN >> 5;
    __shared__ bf16 in_lds[2][672 * 32];      // 86,016 B
    __shared__ bf16 w_lds[2][36 * 512];       // 73,728 B  (total 159,744)

    const int wg = blockIdx.x;                // 512 blocks
    const int v  = (wg & 7) * 64 + (wg >> 3); // bijective XCD chunking
    const int tile = v & 31, b = v >> 5;
    const int x0 = (tile & 1) * 64;
    const int y0 = (tile >> 1) * 8;
    const int tid  = threadIdx.x;
    const int wid  = tid >> 6;
    const int lane = tid & 63;
    const int lix  = lane & 15, lg = lane >> 4;

    // input staging: 42 wave-chunks of 64 lanes x 16B; wave w owns {w, w+8,..}
    int goff[6]; bool gok[6];
#pragma unroll
    for (int i = 0; i < 6; ++i) {
        int chunk = wid + 8 * i;
        int f = chunk * 64 + lane;
        int pix = f >> 2, u = f & 3;
        int iy = pix / 66, ix = pix - iy * 66;
        int gy = y0 + iy - 1, gx = x0 + ix - 1;
        gok[i]  = (chunk < 42) && (pix < 660) &&
                  (unsigned)gy < 128u && (unsigned)gx < 128u;
        goff[i] = ((b * 128 + gy) * 128 + gx) * CIN + u * 8;
    }
    // bfr read bases (elements): pixel p -> p*32 + lg*8; nj adds 512
    int rd[9];
#pragma unroll
    for (int kg = 0; kg < 3; ++kg)
#pragma unroll
        for (int t = 0; t < 3; ++t)
            rd[kg * 3 + t] = ((wid + kg) * 66 + lix + t) * 32 + lg * 8;

    f32x4 acc[4][4];
#pragma unroll
    for (int i = 0; i < 4; ++i)
#pragma unroll
        for (int j = 0; j < 4; ++j) acc[i][j] = zero4();

    auto issue_in = [&](int cci, int buf) {
#pragma unroll
        for (int i = 0; i < 6; ++i) {
            int chunk = wid + 8 * i;
            if (chunk < 42) {
                const void* src = gok[i] ? (const void*)(in + goff[i] + cci * 32)
                                         : (const void*)zb;
                gll16(src, (char*)&in_lds[buf][0] + chunk * 1024);
            }
        }
    };
    auto issue_w = [&](int cci, int buf) {
#pragma unroll
        for (int i = 0; i < 5; ++i) {
            int chunk = wid + 8 * i;              // = kgt*4 + mi
            if (chunk < 36) {
                const bf16* src = wt + ((size_t)(chunk >> 2) * NC + cci) * 2048
                                     + (chunk & 3) * 512 + lane * 8;
                gll16(src, (char*)&w_lds[buf][0] + chunk * 1024);
            }
        }
    };
    auto compute = [&](int buf) {
#pragma unroll
        for (int kgt = 0; kgt < 9; ++kgt) {
            bf16x8 af[4];
#pragma unroll
            for (int mi = 0; mi < 4; ++mi)
                af[mi] = *(const bf16x8*)&w_lds[buf][(kgt * 4 + mi) * 512 + lane * 8];
#pragma unroll
            for (int nj = 0; nj < 4; ++nj) {
                bf16x8 bfr = *(const bf16x8*)&in_lds[buf][rd[kgt] + nj * 512];
#pragma unroll
                for (int mi = 0; mi < 4; ++mi)
                    acc[mi][nj] = mfma16(af[mi], bfr, acc[mi][nj]);
            }
        }
    };

    issue_in(0, 0);
    issue_w(0, 0);
#pragma unroll 1
    for (int c = 0; c < NC; ++c) {
        if (c + 1 < NC) {
            issue_in(c + 1, (c + 1) & 1);
            issue_w(c + 1, (c + 1) & 1);
            // wait for chunk c's loads only: the newest 11/10/9 (chunk c+1)
            // may stay in flight across the barrier.
            if (wid < 2)      asm volatile("s_waitcnt vmcnt(11)" ::: "memory");
            else if (wid < 4) asm volatile("s_waitcnt vmcnt(10)" ::: "memory");
            else              asm volatile("s_waitcnt vmcnt(9)"  ::: "memory");
        } else {
            asm volatile("s_waitcnt vmcnt(0)" ::: "memory");
        }
        __builtin_amdgcn_s_barrier();           // raw: no implicit vmcnt drain
        __builtin_amdgcn_sched_barrier(0);      // don't hoist ds_reads above
        compute(c & 1);
        __builtin_amdgcn_s_barrier();           // buf reusable next iteration
    }

    if (OUTMODE == 0) {
        // single-pass coalesced store: stage all 8 rows across both in bufs
        bf16* out = (bf16*)outp;
        bf16* stg = &in_lds[0][0];             // [8*64 px][68], 69,632 B
#pragma unroll
        for (int mi = 0; mi < 4; ++mi) {
            float A[4], Bc[4];
#pragma unroll
            for (int r = 0; r < 4; ++r) {
                int c = mi * 16 + lg * 4 + r;
                float s = bg[c] * rsqrtf(bv[c] + EPSV);
                A[r]  = s;
                Bc[r] = bias[c] * s + bb[c] - bm[c] * s;
            }
#pragma unroll
            for (int nj = 0; nj < 4; ++nj) {
                int px = nj * 16 + lix;
                bf16x4 vv;
#pragma unroll
                for (int r = 0; r < 4; ++r)
                    vv[r] = (bf16)(acc[mi][nj][r] * A[r] + Bc[r]);
                *(bf16x4*)&stg[(wid * 64 + px) * 68 + mi * 16 + lg * 4] = vv;
            }
        }
        __syncthreads();
#pragma unroll
        for (int k = 0; k < 8; ++k) {
            int idx = k * 512 + tid;           // 4096 16B-units
            int row = idx >> 9, rem = idx & 511;
            int px = rem >> 3, cu = rem & 7;
            bf16x8 vv = *(const bf16x8*)&stg[(row * 64 + px) * 68 + cu * 8];
            *(bf16x8*)&out[((size_t)((b * 128 + y0 + row) * 128)
                            + x0 + px) * 64 + cu * 8] = vv;
        }
    } else {
        float* out = (float*)outp;
        const int gy = y0 + wid;
#pragma unroll
        for (int mi = 0; mi < 4; ++mi) {
            float A[4], Bc[4];
#pragma unroll
            for (int r = 0; r < 4; ++r) {
                int c = mi * 16 + lg * 4 + r;
                float s = bg[c] * rsqrtf(bv[c] + EPSV);
                A[r]  = s;
                Bc[r] = bias[c] * s + bb[c] - bm[c] * s;
            }
#pragma unroll
            for (int nj = 0; nj < 4; ++nj) {
                int px = x0 + nj * 16 + lix;
                bf16x4 rv = *(const bf16x4*)&resid[((size_t)((b * 128 + gy) * 128) + px) * 64
                                                   + mi * 16 + lg * 4];
#pragma unroll
                for (int r = 0; r < 4; ++r) {
                    int c = mi * 16 + lg * 4 + r;
                    size_t oi = ((size_t)(b * 64 + c) << 14) + (gy << 7) + px;
                    out[oi] = acc[mi][nj][r] * A[r] + Bc[r] + (float)rv[r];
                }
            }
        }
    }
}

// ---------------------------------------------------------------------------
// q[b][n][c] = h[b][4*(n/32)][4*(n%32)][c]
// ---------------------------------------------------------------------------
__global__ __launch_bounds__(256) void gather_q(const bf16* __restrict__ h,
                                                bf16* __restrict__ q)
{
    int t = blockIdx.x * 256 + threadIdx.x;   // < 16*1024*8
    int cu = t & 7, n = (t >> 3) & 1023, b = t >> 13;
    int y = (n >> 5) << 2, x = (n & 31) << 2;
    bf16x8 v = *(const bf16x8*)&h[((size_t)((b * 128 + y) * 128 + x)) * 64 + cu * 8];
    *(bf16x8*)&q[((size_t)(b * 1024 + n)) * 64 + cu * 8] = v;
}

// ---------------------------------------------------------------------------
// Fused flash attention (unchanged).
// ---------------------------------------------------------------------------
__global__ __launch_bounds__(256) void attn_fused(const bf16* __restrict__ q,
                                                  bf16* __restrict__ o)
{
    __shared__ bf16 qn[64 * 72];
    __shared__ bf16 kn[128 * 72];
    __shared__ bf16 vt[64 * 136];
    __shared__ bf16 pl[4][16 * 136];
    __shared__ __align__(16) float fac[4][16];
    const int n0 = blockIdx.x * 64, b = blockIdx.y;
    const int tid = threadIdx.x, w = tid >> 6, lane = tid & 63;
    const int lix = lane & 15, lg = lane >> 4;
    const bf16* qb = q + ((size_t)b << 16);

    for (int f = tid; f < 512; f += 256) {
        int row = f >> 3, cu = f & 7;
        *(bf16x8*)&qn[row * 72 + cu * 8] =
            *(const bf16x8*)&qb[(size_t)(n0 + row) * 64 + cu * 8];
    }

    float m_run = -3.0e38f, l_run = 0.f;
    f32x4 oacc[4];
#pragma unroll
    for (int ct = 0; ct < 4; ++ct) oacc[ct] = zero4();

    for (int mt = 0; mt < 1024; mt += 128) {
        __syncthreads();
        for (int f = tid; f < 1024; f += 256) {
            int row = f >> 3, cu = f & 7;
            *(bf16x8*)&kn[row * 72 + cu * 8] =
                *(const bf16x8*)&qb[(size_t)(mt + row) * 64 + cu * 8];
        }
        for (int f = tid; f < 512; f += 256) {
            int mp = f >> 3, cu = f & 7;
            int m = mp * 2;
            bf16x8 a = *(const bf16x8*)&qb[(size_t)(mt + m) * 64 + cu * 8];
            bf16x8 c = *(const bf16x8*)&qb[(size_t)(mt + m + 1) * 64 + cu * 8];
#pragma unroll
            for (int j = 0; j < 8; ++j) {
                bf16x2 pr = {a[j], c[j]};
                *(bf16x2*)&vt[(cu * 8 + j) * 136 + m] = pr;
            }
        }
        __syncthreads();

        bf16x8 bq0 = *(const bf16x8*)&qn[(w * 16 + lix) * 72 + lg * 8];
        bf16x8 bq1 = *(const bf16x8*)&qn[(w * 16 + lix) * 72 + 32 + lg * 8];

        f32x4 s[8];
#pragma unroll
        for (int t = 0; t < 8; ++t) {
            bf16x8 a0 = *(const bf16x8*)&kn[(t * 16 + lix) * 72 + lg * 8];
            bf16x8 a1 = *(const bf16x8*)&kn[(t * 16 + lix) * 72 + 32 + lg * 8];
            s[t] = mfma16(a0, bq0, zero4());
            s[t] = mfma16(a1, bq1, s[t]);
        }

        float mx = -3.0e38f;
#pragma unroll
        for (int t = 0; t < 8; ++t)
#pragma unroll
            for (int r = 0; r < 4; ++r) { s[t][r] *= 0.125f; mx = fmaxf(mx, s[t][r]); }
        mx = fmaxf(mx, __shfl_xor(mx, 16));
        mx = fmaxf(mx, __shfl_xor(mx, 32));
        float m_new = fmaxf(m_run, mx);
        float alpha = __expf(m_run - m_new);

        float psum = 0.f;
#pragma unroll
        for (int t = 0; t < 8; ++t) {
            float p0 = __expf(s[t][0] - m_new), p1 = __expf(s[t][1] - m_new);
            float p2 = __expf(s[t][2] - m_new), p3 = __expf(s[t][3] - m_new);
            psum += (p0 + p1) + (p2 + p3);
            bf16x2 v01 = {(bf16)p0, (bf16)p1};
            bf16x2 v23 = {(bf16)p2, (bf16)p3};
            *(bf16x2*)&pl[w][lix * 136 + t * 16 + lg * 4]     = v01;
            *(bf16x2*)&pl[w][lix * 136 + t * 16 + lg * 4 + 2] = v23;
        }
        psum += __shfl_xor(psum, 16);
        psum += __shfl_xor(psum, 32);
        l_run = l_run * alpha + psum;
        m_run = m_new;
        if (lg == 0) fac[w][lix] = alpha;

        float4 a4 = *(const float4*)&fac[w][lg * 4];
        float aa[4] = {a4.x, a4.y, a4.z, a4.w};
#pragma unroll
        for (int ct = 0; ct < 4; ++ct)
#pragma unroll
            for (int r = 0; r < 4; ++r) oacc[ct][r] *= aa[r];

#pragma unroll
        for (int kk = 0; kk < 4; ++kk) {
            bf16x8 pa = *(const bf16x8*)&pl[w][lix * 136 + kk * 32 + lg * 8];
#pragma unroll
            for (int ct = 0; ct < 4; ++ct) {
                bf16x8 bv = *(const bf16x8*)&vt[(ct * 16 + lix) * 136 + kk * 32 + lg * 8];
                oacc[ct] = mfma16(pa, bv, oacc[ct]);
            }
        }
    }

    if (lg == 0) fac[w][lix] = l_run;
    float4 l4 = *(const float4*)&fac[w][lg * 4];
    float ll[4] = {1.f / l4.x, 1.f / l4.y, 1.f / l4.z, 1.f / l4.w};
#pragma unroll
    for (int ct = 0; ct < 4; ++ct)
#pragma unroll
        for (int r = 0; r < 4; ++r) {
            int n = n0 + w * 16 + lg * 4 + r;
            int c = ct * 16 + lix;
            o[((size_t)(b * 1024 + n)) * 64 + c] = (bf16)(oacc[ct][r] * ll[r]);
        }
}

// ---------------------------------------------------------------------------
// conv1x1 (128->128) + BN + fast exact GELU; coalesced store via LDS.
// ---------------------------------------------------------------------------
__global__ __launch_bounds__(256) void conv1x1_mfma(
    const bf16* __restrict__ h, const bf16* __restrict__ ov,
    const bf16* __restrict__ wt, const float* __restrict__ bias,
    const float* __restrict__ bg, const float* __restrict__ bb,
    const float* __restrict__ bm, const float* __restrict__ bv,
    bf16* __restrict__ g)
{
    __shared__ bf16 in1[128 * 136];           // 34,816 B (reused as out-stage)
    const int y = blockIdx.x, b = blockIdx.y;
    const int tid = threadIdx.x;
    const int wid = tid >> 6, lane = tid & 63;
    const int lix = lane & 15, lg = lane >> 4;
    const int wm = wid >> 1, wn = wid & 1;

    for (int f = tid; f < 128 * 16; f += 256) {
        int px = f >> 4, cu = f & 15;
        bf16x8 v;
        if (cu < 8) {
            v = *(const bf16x8*)&h[((size_t)((b * 128 + y) * 128 + px)) * 64 + cu * 8];
        } else {
            int n = ((y >> 2) << 5) + (px >> 2);
            v = *(const bf16x8*)&ov[((size_t)(b * 1024 + n)) * 64 + (cu - 8) * 8];
        }
        *(bf16x8*)&in1[px * 136 + cu * 8] = v;
    }
    __syncthreads();

    f32x4 acc[4][4];
#pragma unroll
    for (int i = 0; i < 4; ++i)
#pragma unroll
        for (int j = 0; j < 4; ++j) acc[i][j] = zero4();

#pragma unroll
    for (int ks = 0; ks < 4; ++ks) {
        bf16x8 af[4], bfv[4];
#pragma unroll
        for (int mi = 0; mi < 4; ++mi)
            af[mi] = *(const bf16x8*)&wt[(((size_t)(ks * 4 + lg) * 128) + wm * 64 + mi * 16 + lix) * 8];
#pragma unroll
        for (int nj = 0; nj < 4; ++nj)
            bfv[nj] = *(const bf16x8*)&in1[(wn * 64 + nj * 16 + lix) * 136 + ks * 32 + lg * 8];
#pragma unroll
        for (int mi = 0; mi < 4; ++mi)
#pragma unroll
            for (int nj = 0; nj < 4; ++nj)
                acc[mi][nj] = mfma16(af[mi], bfv[nj], acc[mi][nj]);
    }

    __syncthreads();                           // done reading in1
    bf16* stg = in1;                           // [128 px][132] view
#pragma unroll
    for (int mi = 0; mi < 4; ++mi) {
        float A[4], Bc[4];
#pragma unroll
        for (int r = 0; r < 4; ++r) {
            int c = wm * 64 + mi * 16 + lg * 4 + r;
            float s = bg[c] * rsqrtf(bv[c] + EPSV);
            A[r]  = s;
            Bc[r] = bias[c] * s + bb[c] - bm[c] * s;
        }
#pragma unroll
        for (int nj = 0; nj < 4; ++nj) {
            int px = wn * 64 + nj * 16 + lix;
            bf16x4 vv;
#pragma unroll
            for (int r = 0; r < 4; ++r)
                vv[r] = (bf16)gelu_f(acc[mi][nj][r] * A[r] + Bc[r]);
            *(bf16x4*)&stg[px * 132 + wm * 64 + mi * 16 + lg * 4] = vv;
        }
    }
    __syncthreads();
#pragma unroll
    for (int k = 0; k < 8; ++k) {
        int idx = k * 256 + tid;               // 2048 16B-units
        int px = idx >> 4, cu = idx & 15;
        bf16x8 v = *(const bf16x8*)&stg[px * 132 + cu * 8];
        *(bf16x8*)&g[((size_t)((b * 128 + y) * 128) + px) * 128 + cu * 8] = v;
    }
}

// ---------------------------------------------------------------------------
extern "C" void kernel_launch(void* const* d_in, const int* in_sizes, int n_in,
                              void* d_out, int out_size, void* d_ws, size_t ws_size,
                              hipStream_t stream)
{
    const float* x     = (const float*)d_in[0];
    const float* fc1_w = (const float*)d_in[1];
    const float* fc1_b = (const float*)d_in[2];
    const float* bn1_g = (const float*)d_in[3];
    const float* bn1_b = (const float*)d_in[4];
    const float* bn1_m = (const float*)d_in[5];
    const float* bn1_v = (const float*)d_in[6];
    const float* gc_w  = (const float*)d_in[7];
    const float* gc_b  = (const float*)d_in[8];
    const float* bng_g = (const float*)d_in[9];
    const float* bng_b = (const float*)d_in[10];
    const float* bng_m = (const float*)d_in[11];
    const float* bng_v = (const float*)d_in[12];
    const float* fc2_w = (const float*)d_in[13];
    const float* fc2_b = (const float*)d_in[14];
    const float* bn2_g = (const float*)d_in[15];
    const float* bn2_b = (const float*)d_in[16];
    const float* bn2_m = (const float*)d_in[17];
    const float* bn2_v = (const float*)d_in[18];

    char* wsb = (char*)d_ws;
    bf16* x_bf = (bf16*)wsb;                      // 33,554,432 B
    bf16* h    = (bf16*)(wsb + 33554432);         // 33,554,432 B
    bf16* g    = (bf16*)(wsb + 67108864);         // 67,108,864 B
    bf16* q    = (bf16*)(wsb + 134217728);        //  2,097,152 B
    bf16* o    = (bf16*)(wsb + 136314880);        //  2,097,152 B
    bf16* wt1  = (bf16*)(wsb + 138412032);        //     73,728 B
    bf16* wt2  = (bf16*)(wsb + 138485760);        //    147,456 B
    bf16* wtg  = (bf16*)(wsb + 138633216);        //     32,768 B
    bf16* zb   = (bf16*)(wsb + 138665984);        //      1,024 B

    prep_conv_w<64><<<16, 256, 0, stream>>>(fc1_w, wt1);
    prep_conv_w<128><<<32, 256, 0, stream>>>(fc2_w, wt2);
    prep_1x1_w<<<64, 256, 0, stream>>>(gc_w, wtg);

    cvt_x_nhwc<<<dim3(256, 16), 256, 0, stream>>>(x, x_bf, (float*)zb);

    conv3x3_mfma<64, 0><<<512, 512, 0, stream>>>(
        x_bf, wt1, fc1_b, bn1_g, bn1_b, bn1_m, bn1_v, nullptr, zb, h);

    gather_q<<<512, 256, 0, stream>>>(h, q);

    attn_fused<<<dim3(16, 16), 256, 0, stream>>>(q, o);

    conv1x1_mfma<<<dim3(128, 16), 256, 0, stream>>>(
        h, o, wtg, gc_b, bng_g, bng_b, bng_m, bng_v, g);

    conv3x3_mfma<128, 1><<<512, 512, 0, stream>>>(
        g, wt2, fc2_b, bn2_g, bn2_b, bn2_m, bn2_v, x_bf, zb, (float*)d_out);
}

// Round 10
// 186.629 us; speedup vs baseline: 1.0491x; 1.0003x over previous
//
#include <hip/hip_runtime.h>
#include <math.h>

#define EPSV 1e-5f

typedef __bf16 bf16;
using bf16x8 = __attribute__((ext_vector_type(8))) __bf16;
using bf16x4 = __attribute__((ext_vector_type(4))) __bf16;
using bf16x2 = __attribute__((ext_vector_type(2))) __bf16;
using f32x4  = __attribute__((ext_vector_type(4))) float;

static __device__ __forceinline__ f32x4 mfma16(bf16x8 a, bf16x8 b, f32x4 c) {
    return __builtin_amdgcn_mfma_f32_16x16x32_bf16(a, b, c, 0, 0, 0);
}
static __device__ __forceinline__ f32x4 zero4() {
    f32x4 z = {0.f, 0.f, 0.f, 0.f};
    return z;
}

// async global->LDS, 16B per lane. LDS dst = wave-uniform base + lane*16;
// global src is per-lane.
typedef __attribute__((address_space(1))) const char g_char_t;
typedef __attribute__((address_space(3))) char lds_char_t;
static __device__ __forceinline__ void gll16(const void* g, void* l) {
    __builtin_amdgcn_global_load_lds((g_char_t*)g, (lds_char_t*)l, 16, 0, 0);
}

// exact-GELU via Abramowitz-Stegun 7.1.26 erf (|err| <= 1.5e-7)
static __device__ __forceinline__ float gelu_f(float v) {
    float z = fabsf(v) * 0.70710678118f;
    float t = __builtin_amdgcn_rcpf(1.f + 0.3275911f * z);
    float poly = t * (0.254829592f + t * (-0.284496736f + t * (1.421413741f +
                 t * (-1.453152027f + t * 1.061405429f))));
    float e = __expf(-z * z);
    float erfv = copysignf(1.f - poly * e, v);
    return 0.5f * v * (1.f + erfv);
}

// ---------------------------------------------------------------------------
// Weight prep: conv3x3 fp32 [cout][CIN][3][3] -> bf16 LANE-LINEAR fragments:
// wt[(((kgt*NC+cci)*4 + mi)*64 + lane)*8 + j] where lane = lg*16+lix,
// cout = mi*16+lix, ci = cci*32+lg*8+j. A wave's (kgt,mi) fragment is a
// contiguous 1KB block readable at base+lane*16 (gll16- and LDS-linear).
// ---------------------------------------------------------------------------
template<int CIN>
__global__ __launch_bounds__(256) void prep_conv_w(const float* __restrict__ w,
                                                   bf16* __restrict__ wt)
{
    int t = blockIdx.x * 256 + threadIdx.x;      // cout*CIN + ci
    if (t >= 64 * CIN) return;
    int cout = t / CIN, ci = t - cout * CIN;
    int cci = ci >> 5, lg = (ci >> 3) & 3, j = ci & 7;
    int mi = cout >> 4, lix = cout & 15;
#pragma unroll
    for (int kgt = 0; kgt < 9; ++kgt) {
        float v = w[(size_t)t * 9 + kgt];
        wt[((((size_t)kgt * (CIN >> 5) + cci) * 4 + mi) * 64 + lg * 16 + lix) * 8 + j]
            = (bf16)v;
    }
}

// gc_w fp32 [128][128] -> wt[(((ks*4+lg)*128)+cout)*8+j]
__global__ __launch_bounds__(256) void prep_1x1_w(const float* __restrict__ w,
                                                  bf16* __restrict__ wt)
{
    int t = blockIdx.x * 256 + threadIdx.x;      // cout*128+ci, 16384
    int cout = t >> 7, ci = t & 127;
    int ks = ci >> 5, lg = (ci >> 3) & 3, j = ci & 7;
    wt[(((size_t)(ks * 4 + lg) * 128) + cout) * 8 + j] = (bf16)w[t];
}

// ---------------------------------------------------------------------------
// x fp32 NCHW -> bf16 NHWC; also zeroes the 1KB OOB-source scratch region.
// ---------------------------------------------------------------------------
__global__ __launch_bounds__(256) void cvt_x_nhwc(const float* __restrict__ x,
                                                  bf16* __restrict__ xb,
                                                  float* __restrict__ zb)
{
    __shared__ float t_lds[64 * 68];
    const int bx = blockIdx.x;          // y = bx>>1, half = bx&1
    const int b  = blockIdx.y;
    const int y  = bx >> 1, x0 = (bx & 1) * 64;
    const int tid = threadIdx.x;

    if (bx == 0 && b == 0 && tid < 64)
        ((float4*)zb)[tid] = make_float4(0.f, 0.f, 0.f, 0.f);

    for (int f = tid; f < 64 * 16; f += 256) {
        int c = f >> 4, xu = f & 15;
        float4 v = *(const float4*)&x[((size_t)(b * 64 + c) << 14) + (y << 7) + x0 + xu * 4];
        t_lds[(xu * 4 + 0) * 68 + c] = v.x;
        t_lds[(xu * 4 + 1) * 68 + c] = v.y;
        t_lds[(xu * 4 + 2) * 68 + c] = v.z;
        t_lds[(xu * 4 + 3) * 68 + c] = v.w;
    }
    __syncthreads();
    for (int f = tid; f < 64 * 8; f += 256) {
        int xx = f >> 3, cu = f & 7;
        const float* p = &t_lds[xx * 68 + cu * 8];
        bf16x8 v;
#pragma unroll
        for (int j = 0; j < 8; ++j) v[j] = (bf16)p[j];
        *(bf16x8*)&xb[((size_t)((b * 128 + y) * 128) + x0 + xx) * 64 + cu * 8] = v;
    }
}

// ---------------------------------------------------------------------------
// conv3x3 MFMA implicit GEMM v10: per-kgt rotated register pipeline.
// Block = 512 thr = 8 waves; wave = one y-row, tile = 8 rows x 64 px,
// wave tile 64 cout x 64 px (mi=4, nj=4).
// Input + weights double-buffered in LDS (gll16, counted vmcnt, raw
// barriers). NEW: compute() rotates TWO register fragment sets so kgt+1's
// 8 ds_reads are issued BEFORE kgt's 16 MFMAs (sched_barrier-pinned
// phases) -> LDS pipe overlaps the matrix pipe instead of serializing.
// OUTMODE 0: bf16 NHWC + BN, coalesced single-pass LDS-staged store.
// OUTMODE 1: fp32 NCHW + BN + residual(bf16 NHWC).
// ---------------------------------------------------------------------------
template<int CIN, int OUTMODE>
__global__ __launch_bounds__(512) void conv3x3_mfma(
    const bf16* __restrict__ in, const bf16* __restrict__ wt,
    const float* __restrict__ bias,
    const float* __restrict__ bg, const float* __restrict__ bb,
    const float* __restrict__ bm, const float* __restrict__ bv,
    const bf16* __restrict__ resid, const bf16* __restrict__ zb,
    void* __restrict__ outp)
{
    constexpr int NC = CIN >> 5;
    __shared__ bf16 in_lds[2][672 * 32];      // 86,016 B
    __shared__ bf16 w_lds[2][36 * 512];       // 73,728 B  (total 159,744)

    const int wg = blockIdx.x;                // 512 blocks
    const int v  = (wg & 7) * 64 + (wg >> 3); // bijective XCD chunking
    const int tile = v & 31, b = v >> 5;
    const int x0 = (tile & 1) * 64;
    const int y0 = (tile >> 1) * 8;
    const int tid  = threadIdx.x;
    const int wid  = tid >> 6;
    const int lane = tid & 63;
    const int lix  = lane & 15, lg = lane >> 4;

    // input staging: 42 wave-chunks of 64 lanes x 16B; wave w owns {w, w+8,..}
    int goff[6]; bool gok[6];
#pragma unroll
    for (int i = 0; i < 6; ++i) {
        int chunk = wid + 8 * i;
        int f = chunk * 64 + lane;
        int pix = f >> 2, u = f & 3;
        int iy = pix / 66, ix = pix - iy * 66;
        int gy = y0 + iy - 1, gx = x0 + ix - 1;
        gok[i]  = (chunk < 42) && (pix < 660) &&
                  (unsigned)gy < 128u && (unsigned)gx < 128u;
        goff[i] = ((b * 128 + gy) * 128 + gx) * CIN + u * 8;
    }
    // bfr read bases (elements): pixel p -> p*32 + lg*8; nj adds 512
    int rd[9];
#pragma unroll
    for (int kg = 0; kg < 3; ++kg)
#pragma unroll
        for (int t = 0; t < 3; ++t)
            rd[kg * 3 + t] = ((wid + kg) * 66 + lix + t) * 32 + lg * 8;

    f32x4 acc[4][4];
#pragma unroll
    for (int i = 0; i < 4; ++i)
#pragma unroll
        for (int j = 0; j < 4; ++j) acc[i][j] = zero4();

    auto issue_in = [&](int cci, int buf) {
#pragma unroll
        for (int i = 0; i < 6; ++i) {
            int chunk = wid + 8 * i;
            if (chunk < 42) {
                const void* src = gok[i] ? (const void*)(in + goff[i] + cci * 32)
                                         : (const void*)zb;
                gll16(src, (char*)&in_lds[buf][0] + chunk * 1024);
            }
        }
    };
    auto issue_w = [&](int cci, int buf) {
#pragma unroll
        for (int i = 0; i < 5; ++i) {
            int chunk = wid + 8 * i;              // = kgt*4 + mi
            if (chunk < 36) {
                const bf16* src = wt + ((size_t)(chunk >> 2) * NC + cci) * 2048
                                     + (chunk & 3) * 512 + lane * 8;
                gll16(src, (char*)&w_lds[buf][0] + chunk * 1024);
            }
        }
    };
    // rotated-register pipelined compute: issue kgt+1's frag loads before
    // kgt's MFMAs; sched_barrier(0) pins the phase boundaries.
    auto compute = [&](int buf) {
        bf16x8 afA[4], bfA[4], afB[4], bfB[4];
#pragma unroll
        for (int mi = 0; mi < 4; ++mi)
            afA[mi] = *(const bf16x8*)&w_lds[buf][(0 * 4 + mi) * 512 + lane * 8];
#pragma unroll
        for (int nj = 0; nj < 4; ++nj)
            bfA[nj] = *(const bf16x8*)&in_lds[buf][rd[0] + nj * 512];
#pragma unroll
        for (int kgt = 0; kgt < 9; ++kgt) {
            bf16x8* afC = (kgt & 1) ? afB : afA;
            bf16x8* bfC = (kgt & 1) ? bfB : bfA;
            bf16x8* afN = (kgt & 1) ? afA : afB;
            bf16x8* bfN = (kgt & 1) ? bfA : bfB;
            if (kgt < 8) {
#pragma unroll
                for (int mi = 0; mi < 4; ++mi)
                    afN[mi] = *(const bf16x8*)&w_lds[buf][((kgt + 1) * 4 + mi) * 512 + lane * 8];
#pragma unroll
                for (int nj = 0; nj < 4; ++nj)
                    bfN[nj] = *(const bf16x8*)&in_lds[buf][rd[kgt + 1] + nj * 512];
            }
            __builtin_amdgcn_sched_barrier(0);
#pragma unroll
            for (int nj = 0; nj < 4; ++nj)
#pragma unroll
                for (int mi = 0; mi < 4; ++mi)
                    acc[mi][nj] = mfma16(afC[mi], bfC[nj], acc[mi][nj]);
            __builtin_amdgcn_sched_barrier(0);
        }
    };

    issue_in(0, 0);
    issue_w(0, 0);
#pragma unroll 1
    for (int c = 0; c < NC; ++c) {
        if (c + 1 < NC) {
            issue_in(c + 1, (c + 1) & 1);
            issue_w(c + 1, (c + 1) & 1);
            // wait for chunk c's loads only: the newest 11/10/9 (chunk c+1)
            // may stay in flight across the barrier.
            if (wid < 2)      asm volatile("s_waitcnt vmcnt(11)" ::: "memory");
            else if (wid < 4) asm volatile("s_waitcnt vmcnt(10)" ::: "memory");
            else              asm volatile("s_waitcnt vmcnt(9)"  ::: "memory");
        } else {
            asm volatile("s_waitcnt vmcnt(0)" ::: "memory");
        }
        __builtin_amdgcn_s_barrier();           // raw: no implicit vmcnt drain
        __builtin_amdgcn_sched_barrier(0);      // don't hoist ds_reads above
        compute(c & 1);
        __builtin_amdgcn_s_barrier();           // buf reusable next iteration
    }

    if (OUTMODE == 0) {
        // single-pass coalesced store: stage all 8 rows across both in bufs
        bf16* out = (bf16*)outp;
        bf16* stg = &in_lds[0][0];             // [8*64 px][68], 69,632 B
#pragma unroll
        for (int mi = 0; mi < 4; ++mi) {
            float A[4], Bc[4];
#pragma unroll
            for (int r = 0; r < 4; ++r) {
                int c = mi * 16 + lg * 4 + r;
                float s = bg[c] * rsqrtf(bv[c] + EPSV);
                A[r]  = s;
                Bc[r] = bias[c] * s + bb[c] - bm[c] * s;
            }
#pragma unroll
            for (int nj = 0; nj < 4; ++nj) {
                int px = nj * 16 + lix;
                bf16x4 vv;
#pragma unroll
                for (int r = 0; r < 4; ++r)
                    vv[r] = (bf16)(acc[mi][nj][r] * A[r] + Bc[r]);
                *(bf16x4*)&stg[(wid * 64 + px) * 68 + mi * 16 + lg * 4] = vv;
            }
        }
        __syncthreads();
#pragma unroll
        for (int k = 0; k < 8; ++k) {
            int idx = k * 512 + tid;           // 4096 16B-units
            int row = idx >> 9, rem = idx & 511;
            int px = rem >> 3, cu = rem & 7;
            bf16x8 vv = *(const bf16x8*)&stg[(row * 64 + px) * 68 + cu * 8];
            *(bf16x8*)&out[((size_t)((b * 128 + y0 + row) * 128)
                            + x0 + px) * 64 + cu * 8] = vv;
        }
    } else {
        float* out = (float*)outp;
        const int gy = y0 + wid;
#pragma unroll
        for (int mi = 0; mi < 4; ++mi) {
            float A[4], Bc[4];
#pragma unroll
            for (int r = 0; r < 4; ++r) {
                int c = mi * 16 + lg * 4 + r;
                float s = bg[c] * rsqrtf(bv[c] + EPSV);
                A[r]  = s;
                Bc[r] = bias[c] * s + bb[c] - bm[c] * s;
            }
#pragma unroll
            for (int nj = 0; nj < 4; ++nj) {
                int px = x0 + nj * 16 + lix;
                bf16x4 rv = *(const bf16x4*)&resid[((size_t)((b * 128 + gy) * 128) + px) * 64
                                                   + mi * 16 + lg * 4];
#pragma unroll
                for (int r = 0; r < 4; ++r) {
                    int c = mi * 16 + lg * 4 + r;
                    size_t oi = ((size_t)(b * 64 + c) << 14) + (gy << 7) + px;
                    out[oi] = acc[mi][nj][r] * A[r] + Bc[r] + (float)rv[r];
                }
            }
        }
    }
}

// ---------------------------------------------------------------------------
// q[b][n][c] = h[b][4*(n/32)][4*(n%32)][c]
// ---------------------------------------------------------------------------
__global__ __launch_bounds__(256) void gather_q(const bf16* __restrict__ h,
                                                bf16* __restrict__ q)
{
    int t = blockIdx.x * 256 + threadIdx.x;   // < 16*1024*8
    int cu = t & 7, n = (t >> 3) & 1023, b = t >> 13;
    int y = (n >> 5) << 2, x = (n & 31) << 2;
    bf16x8 v = *(const bf16x8*)&h[((size_t)((b * 128 + y) * 128 + x)) * 64 + cu * 8];
    *(bf16x8*)&q[((size_t)(b * 1024 + n)) * 64 + cu * 8] = v;
}

// ---------------------------------------------------------------------------
// Fused flash attention (unchanged).
// ---------------------------------------------------------------------------
__global__ __launch_bounds__(256) void attn_fused(const bf16* __restrict__ q,
                                                  bf16* __restrict__ o)
{
    __shared__ bf16 qn[64 * 72];
    __shared__ bf16 kn[128 * 72];
    __shared__ bf16 vt[64 * 136];
    __shared__ bf16 pl[4][16 * 136];
    __shared__ __align__(16) float fac[4][16];
    const int n0 = blockIdx.x * 64, b = blockIdx.y;
    const int tid = threadIdx.x, w = tid >> 6, lane = tid & 63;
    const int lix = lane & 15, lg = lane >> 4;
    const bf16* qb = q + ((size_t)b << 16);

    for (int f = tid; f < 512; f += 256) {
        int row = f >> 3, cu = f & 7;
        *(bf16x8*)&qn[row * 72 + cu * 8] =
            *(const bf16x8*)&qb[(size_t)(n0 + row) * 64 + cu * 8];
    }

    float m_run = -3.0e38f, l_run = 0.f;
    f32x4 oacc[4];
#pragma unroll
    for (int ct = 0; ct < 4; ++ct) oacc[ct] = zero4();

    for (int mt = 0; mt < 1024; mt += 128) {
        __syncthreads();
        for (int f = tid; f < 1024; f += 256) {
            int row = f >> 3, cu = f & 7;
            *(bf16x8*)&kn[row * 72 + cu * 8] =
                *(const bf16x8*)&qb[(size_t)(mt + row) * 64 + cu * 8];
        }
        for (int f = tid; f < 512; f += 256) {
            int mp = f >> 3, cu = f & 7;
            int m = mp * 2;
            bf16x8 a = *(const bf16x8*)&qb[(size_t)(mt + m) * 64 + cu * 8];
            bf16x8 c = *(const bf16x8*)&qb[(size_t)(mt + m + 1) * 64 + cu * 8];
#pragma unroll
            for (int j = 0; j < 8; ++j) {
                bf16x2 pr = {a[j], c[j]};
                *(bf16x2*)&vt[(cu * 8 + j) * 136 + m] = pr;
            }
        }
        __syncthreads();

        bf16x8 bq0 = *(const bf16x8*)&qn[(w * 16 + lix) * 72 + lg * 8];
        bf16x8 bq1 = *(const bf16x8*)&qn[(w * 16 + lix) * 72 + 32 + lg * 8];

        f32x4 s[8];
#pragma unroll
        for (int t = 0; t < 8; ++t) {
            bf16x8 a0 = *(const bf16x8*)&kn[(t * 16 + lix) * 72 + lg * 8];
            bf16x8 a1 = *(const bf16x8*)&kn[(t * 16 + lix) * 72 + 32 + lg * 8];
            s[t] = mfma16(a0, bq0, zero4());
            s[t] = mfma16(a1, bq1, s[t]);
        }

        float mx = -3.0e38f;
#pragma unroll
        for (int t = 0; t < 8; ++t)
#pragma unroll
            for (int r = 0; r < 4; ++r) { s[t][r] *= 0.125f; mx = fmaxf(mx, s[t][r]); }
        mx = fmaxf(mx, __shfl_xor(mx, 16));
        mx = fmaxf(mx, __shfl_xor(mx, 32));
        float m_new = fmaxf(m_run, mx);
        float alpha = __expf(m_run - m_new);

        float psum = 0.f;
#pragma unroll
        for (int t = 0; t < 8; ++t) {
            float p0 = __expf(s[t][0] - m_new), p1 = __expf(s[t][1] - m_new);
            float p2 = __expf(s[t][2] - m_new), p3 = __expf(s[t][3] - m_new);
            psum += (p0 + p1) + (p2 + p3);
            bf16x2 v01 = {(bf16)p0, (bf16)p1};
            bf16x2 v23 = {(bf16)p2, (bf16)p3};
            *(bf16x2*)&pl[w][lix * 136 + t * 16 + lg * 4]     = v01;
            *(bf16x2*)&pl[w][lix * 136 + t * 16 + lg * 4 + 2] = v23;
        }
        psum += __shfl_xor(psum, 16);
        psum += __shfl_xor(psum, 32);
        l_run = l_run * alpha + psum;
        m_run = m_new;
        if (lg == 0) fac[w][lix] = alpha;

        float4 a4 = *(const float4*)&fac[w][lg * 4];
        float aa[4] = {a4.x, a4.y, a4.z, a4.w};
#pragma unroll
        for (int ct = 0; ct < 4; ++ct)
#pragma unroll
            for (int r = 0; r < 4; ++r) oacc[ct][r] *= aa[r];

#pragma unroll
        for (int kk = 0; kk < 4; ++kk) {
            bf16x8 pa = *(const bf16x8*)&pl[w][lix * 136 + kk * 32 + lg * 8];
#pragma unroll
            for (int ct = 0; ct < 4; ++ct) {
                bf16x8 bv = *(const bf16x8*)&vt[(ct * 16 + lix) * 136 + kk * 32 + lg * 8];
                oacc[ct] = mfma16(pa, bv, oacc[ct]);
            }
        }
    }

    if (lg == 0) fac[w][lix] = l_run;
    float4 l4 = *(const float4*)&fac[w][lg * 4];
    float ll[4] = {1.f / l4.x, 1.f / l4.y, 1.f / l4.z, 1.f / l4.w};
#pragma unroll
    for (int ct = 0; ct < 4; ++ct)
#pragma unroll
        for (int r = 0; r < 4; ++r) {
            int n = n0 + w * 16 + lg * 4 + r;
            int c = ct * 16 + lix;
            o[((size_t)(b * 1024 + n)) * 64 + c] = (bf16)(oacc[ct][r] * ll[r]);
        }
}

// ---------------------------------------------------------------------------
// conv1x1 (128->128) + BN + fast exact GELU; coalesced store via LDS.
// ---------------------------------------------------------------------------
__global__ __launch_bounds__(256) void conv1x1_mfma(
    const bf16* __restrict__ h, const bf16* __restrict__ ov,
    const bf16* __restrict__ wt, const float* __restrict__ bias,
    const float* __restrict__ bg, const float* __restrict__ bb,
    const float* __restrict__ bm, const float* __restrict__ bv,
    bf16* __restrict__ g)
{
    __shared__ bf16 in1[128 * 136];           // 34,816 B (reused as out-stage)
    const int y = blockIdx.x, b = blockIdx.y;
    const int tid = threadIdx.x;
    const int wid = tid >> 6, lane = tid & 63;
    const int lix = lane & 15, lg = lane >> 4;
    const int wm = wid >> 1, wn = wid & 1;

    for (int f = tid; f < 128 * 16; f += 256) {
        int px = f >> 4, cu = f & 15;
        bf16x8 v;
        if (cu < 8) {
            v = *(const bf16x8*)&h[((size_t)((b * 128 + y) * 128 + px)) * 64 + cu * 8];
        } else {
            int n = ((y >> 2) << 5) + (px >> 2);
            v = *(const bf16x8*)&ov[((size_t)(b * 1024 + n)) * 64 + (cu - 8) * 8];
        }
        *(bf16x8*)&in1[px * 136 + cu * 8] = v;
    }
    __syncthreads();

    f32x4 acc[4][4];
#pragma unroll
    for (int i = 0; i < 4; ++i)
#pragma unroll
        for (int j = 0; j < 4; ++j) acc[i][j] = zero4();

#pragma unroll
    for (int ks = 0; ks < 4; ++ks) {
        bf16x8 af[4], bfv[4];
#pragma unroll
        for (int mi = 0; mi < 4; ++mi)
            af[mi] = *(const bf16x8*)&wt[(((size_t)(ks * 4 + lg) * 128) + wm * 64 + mi * 16 + lix) * 8];
#pragma unroll
        for (int nj = 0; nj < 4; ++nj)
            bfv[nj] = *(const bf16x8*)&in1[(wn * 64 + nj * 16 + lix) * 136 + ks * 32 + lg * 8];
#pragma unroll
        for (int mi = 0; mi < 4; ++mi)
#pragma unroll
            for (int nj = 0; nj < 4; ++nj)
                acc[mi][nj] = mfma16(af[mi], bfv[nj], acc[mi][nj]);
    }

    __syncthreads();                           // done reading in1
    bf16* stg = in1;                           // [128 px][132] view
#pragma unroll
    for (int mi = 0; mi < 4; ++mi) {
        float A[4], Bc[4];
#pragma unroll
        for (int r = 0; r < 4; ++r) {
            int c = wm * 64 + mi * 16 + lg * 4 + r;
            float s = bg[c] * rsqrtf(bv[c] + EPSV);
            A[r]  = s;
            Bc[r] = bias[c] * s + bb[c] - bm[c] * s;
        }
#pragma unroll
        for (int nj = 0; nj < 4; ++nj) {
            int px = wn * 64 + nj * 16 + lix;
            bf16x4 vv;
#pragma unroll
            for (int r = 0; r < 4; ++r)
                vv[r] = (bf16)gelu_f(acc[mi][nj][r] * A[r] + Bc[r]);
            *(bf16x4*)&stg[px * 132 + wm * 64 + mi * 16 + lg * 4] = vv;
        }
    }
    __syncthreads();
#pragma unroll
    for (int k = 0; k < 8; ++k) {
        int idx = k * 256 + tid;               // 2048 16B-units
        int px = idx >> 4, cu = idx & 15;
        bf16x8 v = *(const bf16x8*)&stg[px * 132 + cu * 8];
        *(bf16x8*)&g[((size_t)((b * 128 + y) * 128) + px) * 128 + cu * 8] = v;
    }
}

// ---------------------------------------------------------------------------
extern "C" void kernel_launch(void* const* d_in, const int* in_sizes, int n_in,
                              void* d_out, int out_size, void* d_ws, size_t ws_size,
                              hipStream_t stream)
{
    const float* x     = (const float*)d_in[0];
    const float* fc1_w = (const float*)d_in[1];
    const float* fc1_b = (const float*)d_in[2];
    const float* bn1_g = (const float*)d_in[3];
    const float* bn1_b = (const float*)d_in[4];
    const float* bn1_m = (const float*)d_in[5];
    const float* bn1_v = (const float*)d_in[6];
    const float* gc_w  = (const float*)d_in[7];
    const float* gc_b  = (const float*)d_in[8];
    const float* bng_g = (const float*)d_in[9];
    const float* bng_b = (const float*)d_in[10];
    const float* bng_m = (const float*)d_in[11];
    const float* bng_v = (const float*)d_in[12];
    const float* fc2_w = (const float*)d_in[13];
    const float* fc2_b = (const float*)d_in[14];
    const float* bn2_g = (const float*)d_in[15];
    const float* bn2_b = (const float*)d_in[16];
    const float* bn2_m = (const float*)d_in[17];
    const float* bn2_v = (const float*)d_in[18];

    char* wsb = (char*)d_ws;
    bf16* x_bf = (bf16*)wsb;                      // 33,554,432 B
    bf16* h    = (bf16*)(wsb + 33554432);         // 33,554,432 B
    bf16* g    = (bf16*)(wsb + 67108864);         // 67,108,864 B
    bf16* q    = (bf16*)(wsb + 134217728);        //  2,097,152 B
    bf16* o    = (bf16*)(wsb + 136314880);        //  2,097,152 B
    bf16* wt1  = (bf16*)(wsb + 138412032);        //     73,728 B
    bf16* wt2  = (bf16*)(wsb + 138485760);        //    147,456 B
    bf16* wtg  = (bf16*)(wsb + 138633216);        //     32,768 B
    bf16* zb   = (bf16*)(wsb + 138665984);        //      1,024 B

    prep_conv_w<64><<<16, 256, 0, stream>>>(fc1_w, wt1);
    prep_conv_w<128><<<32, 256, 0, stream>>>(fc2_w, wt2);
    prep_1x1_w<<<64, 256, 0, stream>>>(gc_w, wtg);

    cvt_x_nhwc<<<dim3(256, 16), 256, 0, stream>>>(x, x_bf, (float*)zb);

    conv3x3_mfma<64, 0><<<512, 512, 0, stream>>>(
        x_bf, wt1, fc1_b, bn1_g, bn1_b, bn1_m, bn1_v, nullptr, zb, h);

    gather_q<<<512, 256, 0, stream>>>(h, q);

    attn_fused<<<dim3(16, 16), 256, 0, stream>>>(q, o);

    conv1x1_mfma<<<dim3(128, 16), 256, 0, stream>>>(
        h, o, wtg, gc_b, bng_g, bng_b, bng_m, bng_v, g);

    conv3x3_mfma<128, 1><<<512, 512, 0, stream>>>(
        g, wt2, fc2_b, bn2_g, bn2_b, bn2_m, bn2_v, x_bf, zb, (float*)d_out);
}

// Round 11
// 185.389 us; speedup vs baseline: 1.0561x; 1.0067x over previous
//
#include <hip/hip_runtime.h>
#include <math.h>

#define EPSV 1e-5f

typedef __bf16 bf16;
using bf16x8 = __attribute__((ext_vector_type(8))) __bf16;
using bf16x4 = __attribute__((ext_vector_type(4))) __bf16;
using bf16x2 = __attribute__((ext_vector_type(2))) __bf16;
using f32x4  = __attribute__((ext_vector_type(4))) float;

static __device__ __forceinline__ f32x4 mfma16(bf16x8 a, bf16x8 b, f32x4 c) {
    return __builtin_amdgcn_mfma_f32_16x16x32_bf16(a, b, c, 0, 0, 0);
}
static __device__ __forceinline__ f32x4 zero4() {
    f32x4 z = {0.f, 0.f, 0.f, 0.f};
    return z;
}

// async global->LDS, 16B per lane. LDS dst = wave-uniform base + lane*16;
// global src is per-lane.
typedef __attribute__((address_space(1))) const char g_char_t;
typedef __attribute__((address_space(3))) char lds_char_t;
static __device__ __forceinline__ void gll16(const void* g, void* l) {
    __builtin_amdgcn_global_load_lds((g_char_t*)g, (lds_char_t*)l, 16, 0, 0);
}

// exact-GELU via Abramowitz-Stegun 7.1.26 erf (|err| <= 1.5e-7)
static __device__ __forceinline__ float gelu_f(float v) {
    float z = fabsf(v) * 0.70710678118f;
    float t = __builtin_amdgcn_rcpf(1.f + 0.3275911f * z);
    float poly = t * (0.254829592f + t * (-0.284496736f + t * (1.421413741f +
                 t * (-1.453152027f + t * 1.061405429f))));
    float e = __expf(-z * z);
    float erfv = copysignf(1.f - poly * e, v);
    return 0.5f * v * (1.f + erfv);
}

// ---------------------------------------------------------------------------
// Weight prep: conv3x3 fp32 [cout][CIN][3][3] -> bf16 LANE-LINEAR fragments:
// wt[(((kgt*NC+cci)*4 + mi)*64 + lane)*8 + j] where lane = lg*16+lix,
// cout = mi*16+lix, ci = cci*32+lg*8+j. A wave's (kgt,mi) fragment is a
// contiguous 1KB block readable at base+lane*16 (gll16- and LDS-linear).
// ---------------------------------------------------------------------------
template<int CIN>
__global__ __launch_bounds__(256) void prep_conv_w(const float* __restrict__ w,
                                                   bf16* __restrict__ wt)
{
    int t = blockIdx.x * 256 + threadIdx.x;      // cout*CIN + ci
    if (t >= 64 * CIN) return;
    int cout = t / CIN, ci = t - cout * CIN;
    int cci = ci >> 5, lg = (ci >> 3) & 3, j = ci & 7;
    int mi = cout >> 4, lix = cout & 15;
#pragma unroll
    for (int kgt = 0; kgt < 9; ++kgt) {
        float v = w[(size_t)t * 9 + kgt];
        wt[((((size_t)kgt * (CIN >> 5) + cci) * 4 + mi) * 64 + lg * 16 + lix) * 8 + j]
            = (bf16)v;
    }
}

// gc_w fp32 [128][128] -> wt[(((ks*4+lg)*128)+cout)*8+j]
__global__ __launch_bounds__(256) void prep_1x1_w(const float* __restrict__ w,
                                                  bf16* __restrict__ wt)
{
    int t = blockIdx.x * 256 + threadIdx.x;      // cout*128+ci, 16384
    int cout = t >> 7, ci = t & 127;
    int ks = ci >> 5, lg = (ci >> 3) & 3, j = ci & 7;
    wt[(((size_t)(ks * 4 + lg) * 128) + cout) * 8 + j] = (bf16)w[t];
}

// ---------------------------------------------------------------------------
// x fp32 NCHW -> bf16 NHWC; also zeroes the 1KB OOB-source scratch region.
// ---------------------------------------------------------------------------
__global__ __launch_bounds__(256) void cvt_x_nhwc(const float* __restrict__ x,
                                                  bf16* __restrict__ xb,
                                                  float* __restrict__ zb)
{
    __shared__ float t_lds[64 * 68];
    const int bx = blockIdx.x;          // y = bx>>1, half = bx&1
    const int b  = blockIdx.y;
    const int y  = bx >> 1, x0 = (bx & 1) * 64;
    const int tid = threadIdx.x;

    if (bx == 0 && b == 0 && tid < 64)
        ((float4*)zb)[tid] = make_float4(0.f, 0.f, 0.f, 0.f);

    for (int f = tid; f < 64 * 16; f += 256) {
        int c = f >> 4, xu = f & 15;
        float4 v = *(const float4*)&x[((size_t)(b * 64 + c) << 14) + (y << 7) + x0 + xu * 4];
        t_lds[(xu * 4 + 0) * 68 + c] = v.x;
        t_lds[(xu * 4 + 1) * 68 + c] = v.y;
        t_lds[(xu * 4 + 2) * 68 + c] = v.z;
        t_lds[(xu * 4 + 3) * 68 + c] = v.w;
    }
    __syncthreads();
    for (int f = tid; f < 64 * 8; f += 256) {
        int xx = f >> 3, cu = f & 7;
        const float* p = &t_lds[xx * 68 + cu * 8];
        bf16x8 v;
#pragma unroll
        for (int j = 0; j < 8; ++j) v[j] = (bf16)p[j];
        *(bf16x8*)&xb[((size_t)((b * 128 + y) * 128) + x0 + xx) * 64 + cu * 8] = v;
    }
}

// ---------------------------------------------------------------------------
// conv3x3 MFMA implicit GEMM v11: v10 + BANK-CONFLICT-FREE bfr reads.
// The [pix][32ci] LDS tile has a 64B pixel stride -> the old read pattern
// (byte = pix*64 + lg*16) put 8 lanes on the same bank quad (8-way).
// Fix (T2, both-sides, linear-LDS): sub-block swizzle s(pix) =
// (pix&3)^((pix>>2)&3); staging fetches global unit u^s(pix) (same 64B
// line -> coalescing intact), reads use unit lg^s(pix). s(pix+16)==s(pix)
// so the nj*512 offset stays valid. gll16 dest remains linear (rule #21).
// ---------------------------------------------------------------------------
template<int CIN, int OUTMODE>
__global__ __launch_bounds__(512) void conv3x3_mfma(
    const bf16* __restrict__ in, const bf16* __restrict__ wt,
    const float* __restrict__ bias,
    const float* __restrict__ bg, const float* __restrict__ bb,
    const float* __restrict__ bm, const float* __restrict__ bv,
    const bf16* __restrict__ resid, const bf16* __restrict__ zb,
    void* __restrict__ outp)
{
    constexpr int NC = CIN >> 5;
    __shared__ bf16 in_lds[2][672 * 32];      // 86,016 B
    __shared__ bf16 w_lds[2][36 * 512];       // 73,728 B  (total 159,744)

    const int wg = blockIdx.x;                // 512 blocks
    const int v  = (wg & 7) * 64 + (wg >> 3); // bijective XCD chunking
    const int tile = v & 31, b = v >> 5;
    const int x0 = (tile & 1) * 64;
    const int y0 = (tile >> 1) * 8;
    const int tid  = threadIdx.x;
    const int wid  = tid >> 6;
    const int lane = tid & 63;
    const int lix  = lane & 15, lg = lane >> 4;

    // input staging: 42 wave-chunks of 64 lanes x 16B; wave w owns {w, w+8,..}
    // source unit is swizzled by s(pix) so the (linear) LDS tile is stored
    // pre-permuted; reads undo it with the same XOR.
    int goff[6]; bool gok[6];
#pragma unroll
    for (int i = 0; i < 6; ++i) {
        int chunk = wid + 8 * i;
        int f = chunk * 64 + lane;
        int pix = f >> 2, u = f & 3;
        int sw = (pix & 3) ^ ((pix >> 2) & 3);
        int ug = u ^ sw;
        int iy = pix / 66, ix = pix - iy * 66;
        int gy = y0 + iy - 1, gx = x0 + ix - 1;
        gok[i]  = (chunk < 42) && (pix < 660) &&
                  (unsigned)gy < 128u && (unsigned)gx < 128u;
        goff[i] = ((b * 128 + gy) * 128 + gx) * CIN + ug * 8;
    }
    // bfr read bases (elements): pixel p -> p*32 + (lg^s(p))*8; nj adds 512
    int rd[9];
#pragma unroll
    for (int kg = 0; kg < 3; ++kg)
#pragma unroll
        for (int t = 0; t < 3; ++t) {
            int pix0 = (wid + kg) * 66 + lix + t;
            int sw = (pix0 & 3) ^ ((pix0 >> 2) & 3);
            rd[kg * 3 + t] = pix0 * 32 + ((lg ^ sw) << 3);
        }

    f32x4 acc[4][4];
#pragma unroll
    for (int i = 0; i < 4; ++i)
#pragma unroll
        for (int j = 0; j < 4; ++j) acc[i][j] = zero4();

    auto issue_in = [&](int cci, int buf) {
#pragma unroll
        for (int i = 0; i < 6; ++i) {
            int chunk = wid + 8 * i;
            if (chunk < 42) {
                const void* src = gok[i] ? (const void*)(in + goff[i] + cci * 32)
                                         : (const void*)zb;
                gll16(src, (char*)&in_lds[buf][0] + chunk * 1024);
            }
        }
    };
    auto issue_w = [&](int cci, int buf) {
#pragma unroll
        for (int i = 0; i < 5; ++i) {
            int chunk = wid + 8 * i;              // = kgt*4 + mi
            if (chunk < 36) {
                const bf16* src = wt + ((size_t)(chunk >> 2) * NC + cci) * 2048
                                     + (chunk & 3) * 512 + lane * 8;
                gll16(src, (char*)&w_lds[buf][0] + chunk * 1024);
            }
        }
    };
    // rotated-register pipelined compute: issue kgt+1's frag loads before
    // kgt's MFMAs; sched_barrier(0) pins the phase boundaries.
    auto compute = [&](int buf) {
        bf16x8 afA[4], bfA[4], afB[4], bfB[4];
#pragma unroll
        for (int mi = 0; mi < 4; ++mi)
            afA[mi] = *(const bf16x8*)&w_lds[buf][(0 * 4 + mi) * 512 + lane * 8];
#pragma unroll
        for (int nj = 0; nj < 4; ++nj)
            bfA[nj] = *(const bf16x8*)&in_lds[buf][rd[0] + nj * 512];
#pragma unroll
        for (int kgt = 0; kgt < 9; ++kgt) {
            bf16x8* afC = (kgt & 1) ? afB : afA;
            bf16x8* bfC = (kgt & 1) ? bfB : bfA;
            bf16x8* afN = (kgt & 1) ? afA : afB;
            bf16x8* bfN = (kgt & 1) ? bfA : bfB;
            if (kgt < 8) {
#pragma unroll
                for (int mi = 0; mi < 4; ++mi)
                    afN[mi] = *(const bf16x8*)&w_lds[buf][((kgt + 1) * 4 + mi) * 512 + lane * 8];
#pragma unroll
                for (int nj = 0; nj < 4; ++nj)
                    bfN[nj] = *(const bf16x8*)&in_lds[buf][rd[kgt + 1] + nj * 512];
            }
            __builtin_amdgcn_sched_barrier(0);
#pragma unroll
            for (int nj = 0; nj < 4; ++nj)
#pragma unroll
                for (int mi = 0; mi < 4; ++mi)
                    acc[mi][nj] = mfma16(afC[mi], bfC[nj], acc[mi][nj]);
            __builtin_amdgcn_sched_barrier(0);
        }
    };

    issue_in(0, 0);
    issue_w(0, 0);
#pragma unroll 1
    for (int c = 0; c < NC; ++c) {
        if (c + 1 < NC) {
            issue_in(c + 1, (c + 1) & 1);
            issue_w(c + 1, (c + 1) & 1);
            // wait for chunk c's loads only: the newest 11/10/9 (chunk c+1)
            // may stay in flight across the barrier.
            if (wid < 2)      asm volatile("s_waitcnt vmcnt(11)" ::: "memory");
            else if (wid < 4) asm volatile("s_waitcnt vmcnt(10)" ::: "memory");
            else              asm volatile("s_waitcnt vmcnt(9)"  ::: "memory");
        } else {
            asm volatile("s_waitcnt vmcnt(0)" ::: "memory");
        }
        __builtin_amdgcn_s_barrier();           // raw: no implicit vmcnt drain
        __builtin_amdgcn_sched_barrier(0);      // don't hoist ds_reads above
        compute(c & 1);
        __builtin_amdgcn_s_barrier();           // buf reusable next iteration
    }

    if (OUTMODE == 0) {
        // single-pass coalesced store: stage all 8 rows across both in bufs
        bf16* out = (bf16*)outp;
        bf16* stg = &in_lds[0][0];             // [8*64 px][68], 69,632 B
#pragma unroll
        for (int mi = 0; mi < 4; ++mi) {
            float A[4], Bc[4];
#pragma unroll
            for (int r = 0; r < 4; ++r) {
                int c = mi * 16 + lg * 4 + r;
                float s = bg[c] * rsqrtf(bv[c] + EPSV);
                A[r]  = s;
                Bc[r] = bias[c] * s + bb[c] - bm[c] * s;
            }
#pragma unroll
            for (int nj = 0; nj < 4; ++nj) {
                int px = nj * 16 + lix;
                bf16x4 vv;
#pragma unroll
                for (int r = 0; r < 4; ++r)
                    vv[r] = (bf16)(acc[mi][nj][r] * A[r] + Bc[r]);
                *(bf16x4*)&stg[(wid * 64 + px) * 68 + mi * 16 + lg * 4] = vv;
            }
        }
        __syncthreads();
#pragma unroll
        for (int k = 0; k < 8; ++k) {
            int idx = k * 512 + tid;           // 4096 16B-units
            int row = idx >> 9, rem = idx & 511;
            int px = rem >> 3, cu = rem & 7;
            bf16x8 vv = *(const bf16x8*)&stg[(row * 64 + px) * 68 + cu * 8];
            *(bf16x8*)&out[((size_t)((b * 128 + y0 + row) * 128)
                            + x0 + px) * 64 + cu * 8] = vv;
        }
    } else {
        float* out = (float*)outp;
        const int gy = y0 + wid;
#pragma unroll
        for (int mi = 0; mi < 4; ++mi) {
            float A[4], Bc[4];
#pragma unroll
            for (int r = 0; r < 4; ++r) {
                int c = mi * 16 + lg * 4 + r;
                float s = bg[c] * rsqrtf(bv[c] + EPSV);
                A[r]  = s;
                Bc[r] = bias[c] * s + bb[c] - bm[c] * s;
            }
#pragma unroll
            for (int nj = 0; nj < 4; ++nj) {
                int px = x0 + nj * 16 + lix;
                bf16x4 rv = *(const bf16x4*)&resid[((size_t)((b * 128 + gy) * 128) + px) * 64
                                                   + mi * 16 + lg * 4];
#pragma unroll
                for (int r = 0; r < 4; ++r) {
                    int c = mi * 16 + lg * 4 + r;
                    size_t oi = ((size_t)(b * 64 + c) << 14) + (gy << 7) + px;
                    out[oi] = acc[mi][nj][r] * A[r] + Bc[r] + (float)rv[r];
                }
            }
        }
    }
}

// ---------------------------------------------------------------------------
// q[b][n][c] = h[b][4*(n/32)][4*(n%32)][c]
// ---------------------------------------------------------------------------
__global__ __launch_bounds__(256) void gather_q(const bf16* __restrict__ h,
                                                bf16* __restrict__ q)
{
    int t = blockIdx.x * 256 + threadIdx.x;   // < 16*1024*8
    int cu = t & 7, n = (t >> 3) & 1023, b = t >> 13;
    int y = (n >> 5) << 2, x = (n & 31) << 2;
    bf16x8 v = *(const bf16x8*)&h[((size_t)((b * 128 + y) * 128 + x)) * 64 + cu * 8];
    *(bf16x8*)&q[((size_t)(b * 1024 + n)) * 64 + cu * 8] = v;
}

// ---------------------------------------------------------------------------
// Fused flash attention (unchanged).
// ---------------------------------------------------------------------------
__global__ __launch_bounds__(256) void attn_fused(const bf16* __restrict__ q,
                                                  bf16* __restrict__ o)
{
    __shared__ bf16 qn[64 * 72];
    __shared__ bf16 kn[128 * 72];
    __shared__ bf16 vt[64 * 136];
    __shared__ bf16 pl[4][16 * 136];
    __shared__ __align__(16) float fac[4][16];
    const int n0 = blockIdx.x * 64, b = blockIdx.y;
    const int tid = threadIdx.x, w = tid >> 6, lane = tid & 63;
    const int lix = lane & 15, lg = lane >> 4;
    const bf16* qb = q + ((size_t)b << 16);

    for (int f = tid; f < 512; f += 256) {
        int row = f >> 3, cu = f & 7;
        *(bf16x8*)&qn[row * 72 + cu * 8] =
            *(const bf16x8*)&qb[(size_t)(n0 + row) * 64 + cu * 8];
    }

    float m_run = -3.0e38f, l_run = 0.f;
    f32x4 oacc[4];
#pragma unroll
    for (int ct = 0; ct < 4; ++ct) oacc[ct] = zero4();

    for (int mt = 0; mt < 1024; mt += 128) {
        __syncthreads();
        for (int f = tid; f < 1024; f += 256) {
            int row = f >> 3, cu = f & 7;
            *(bf16x8*)&kn[row * 72 + cu * 8] =
                *(const bf16x8*)&qb[(size_t)(mt + row) * 64 + cu * 8];
        }
        for (int f = tid; f < 512; f += 256) {
            int mp = f >> 3, cu = f & 7;
            int m = mp * 2;
            bf16x8 a = *(const bf16x8*)&qb[(size_t)(mt + m) * 64 + cu * 8];
            bf16x8 c = *(const bf16x8*)&qb[(size_t)(mt + m + 1) * 64 + cu * 8];
#pragma unroll
            for (int j = 0; j < 8; ++j) {
                bf16x2 pr = {a[j], c[j]};
                *(bf16x2*)&vt[(cu * 8 + j) * 136 + m] = pr;
            }
        }
        __syncthreads();

        bf16x8 bq0 = *(const bf16x8*)&qn[(w * 16 + lix) * 72 + lg * 8];
        bf16x8 bq1 = *(const bf16x8*)&qn[(w * 16 + lix) * 72 + 32 + lg * 8];

        f32x4 s[8];
#pragma unroll
        for (int t = 0; t < 8; ++t) {
            bf16x8 a0 = *(const bf16x8*)&kn[(t * 16 + lix) * 72 + lg * 8];
            bf16x8 a1 = *(const bf16x8*)&kn[(t * 16 + lix) * 72 + 32 + lg * 8];
            s[t] = mfma16(a0, bq0, zero4());
            s[t] = mfma16(a1, bq1, s[t]);
        }

        float mx = -3.0e38f;
#pragma unroll
        for (int t = 0; t < 8; ++t)
#pragma unroll
            for (int r = 0; r < 4; ++r) { s[t][r] *= 0.125f; mx = fmaxf(mx, s[t][r]); }
        mx = fmaxf(mx, __shfl_xor(mx, 16));
        mx = fmaxf(mx, __shfl_xor(mx, 32));
        float m_new = fmaxf(m_run, mx);
        float alpha = __expf(m_run - m_new);

        float psum = 0.f;
#pragma unroll
        for (int t = 0; t < 8; ++t) {
            float p0 = __expf(s[t][0] - m_new), p1 = __expf(s[t][1] - m_new);
            float p2 = __expf(s[t][2] - m_new), p3 = __expf(s[t][3] - m_new);
            psum += (p0 + p1) + (p2 + p3);
            bf16x2 v01 = {(bf16)p0, (bf16)p1};
            bf16x2 v23 = {(bf16)p2, (bf16)p3};
            *(bf16x2*)&pl[w][lix * 136 + t * 16 + lg * 4]     = v01;
            *(bf16x2*)&pl[w][lix * 136 + t * 16 + lg * 4 + 2] = v23;
        }
        psum += __shfl_xor(psum, 16);
        psum += __shfl_xor(psum, 32);
        l_run = l_run * alpha + psum;
        m_run = m_new;
        if (lg == 0) fac[w][lix] = alpha;

        float4 a4 = *(const float4*)&fac[w][lg * 4];
        float aa[4] = {a4.x, a4.y, a4.z, a4.w};
#pragma unroll
        for (int ct = 0; ct < 4; ++ct)
#pragma unroll
            for (int r = 0; r < 4; ++r) oacc[ct][r] *= aa[r];

#pragma unroll
        for (int kk = 0; kk < 4; ++kk) {
            bf16x8 pa = *(const bf16x8*)&pl[w][lix * 136 + kk * 32 + lg * 8];
#pragma unroll
            for (int ct = 0; ct < 4; ++ct) {
                bf16x8 bv = *(const bf16x8*)&vt[(ct * 16 + lix) * 136 + kk * 32 + lg * 8];
                oacc[ct] = mfma16(pa, bv, oacc[ct]);
            }
        }
    }

    if (lg == 0) fac[w][lix] = l_run;
    float4 l4 = *(const float4*)&fac[w][lg * 4];
    float ll[4] = {1.f / l4.x, 1.f / l4.y, 1.f / l4.z, 1.f / l4.w};
#pragma unroll
    for (int ct = 0; ct < 4; ++ct)
#pragma unroll
        for (int r = 0; r < 4; ++r) {
            int n = n0 + w * 16 + lg * 4 + r;
            int c = ct * 16 + lix;
            o[((size_t)(b * 1024 + n)) * 64 + c] = (bf16)(oacc[ct][r] * ll[r]);
        }
}

// ---------------------------------------------------------------------------
// conv1x1 (128->128) + BN + fast exact GELU; coalesced store via LDS.
// ---------------------------------------------------------------------------
__global__ __launch_bounds__(256) void conv1x1_mfma(
    const bf16* __restrict__ h, const bf16* __restrict__ ov,
    const bf16* __restrict__ wt, const float* __restrict__ bias,
    const float* __restrict__ bg, const float* __restrict__ bb,
    const float* __restrict__ bm, const float* __restrict__ bv,
    bf16* __restrict__ g)
{
    __shared__ bf16 in1[128 * 136];           // 34,816 B (reused as out-stage)
    const int y = blockIdx.x, b = blockIdx.y;
    const int tid = threadIdx.x;
    const int wid = tid >> 6, lane = tid & 63;
    const int lix = lane & 15, lg = lane >> 4;
    const int wm = wid >> 1, wn = wid & 1;

    for (int f = tid; f < 128 * 16; f += 256) {
        int px = f >> 4, cu = f & 15;
        bf16x8 v;
        if (cu < 8) {
            v = *(const bf16x8*)&h[((size_t)((b * 128 + y) * 128 + px)) * 64 + cu * 8];
        } else {
            int n = ((y >> 2) << 5) + (px >> 2);
            v = *(const bf16x8*)&ov[((size_t)(b * 1024 + n)) * 64 + (cu - 8) * 8];
        }
        *(bf16x8*)&in1[px * 136 + cu * 8] = v;
    }
    __syncthreads();

    f32x4 acc[4][4];
#pragma unroll
    for (int i = 0; i < 4; ++i)
#pragma unroll
        for (int j = 0; j < 4; ++j) acc[i][j] = zero4();

#pragma unroll
    for (int ks = 0; ks < 4; ++ks) {
        bf16x8 af[4], bfv[4];
#pragma unroll
        for (int mi = 0; mi < 4; ++mi)
            af[mi] = *(const bf16x8*)&wt[(((size_t)(ks * 4 + lg) * 128) + wm * 64 + mi * 16 + lix) * 8];
#pragma unroll
        for (int nj = 0; nj < 4; ++nj)
            bfv[nj] = *(const bf16x8*)&in1[(wn * 64 + nj * 16 + lix) * 136 + ks * 32 + lg * 8];
#pragma unroll
        for (int mi = 0; mi < 4; ++mi)
#pragma unroll
            for (int nj = 0; nj < 4; ++nj)
                acc[mi][nj] = mfma16(af[mi], bfv[nj], acc[mi][nj]);
    }

    __syncthreads();                           // done reading in1
    bf16* stg = in1;                           // [128 px][132] view
#pragma unroll
    for (int mi = 0; mi < 4; ++mi) {
        float A[4], Bc[4];
#pragma unroll
        for (int r = 0; r < 4; ++r) {
            int c = wm * 64 + mi * 16 + lg * 4 + r;
            float s = bg[c] * rsqrtf(bv[c] + EPSV);
            A[r]  = s;
            Bc[r] = bias[c] * s + bb[c] - bm[c] * s;
        }
#pragma unroll
        for (int nj = 0; nj < 4; ++nj) {
            int px = wn * 64 + nj * 16 + lix;
            bf16x4 vv;
#pragma unroll
            for (int r = 0; r < 4; ++r)
                vv[r] = (bf16)gelu_f(acc[mi][nj][r] * A[r] + Bc[r]);
            *(bf16x4*)&stg[px * 132 + wm * 64 + mi * 16 + lg * 4] = vv;
        }
    }
    __syncthreads();
#pragma unroll
    for (int k = 0; k < 8; ++k) {
        int idx = k * 256 + tid;               // 2048 16B-units
        int px = idx >> 4, cu = idx & 15;
        bf16x8 v = *(const bf16x8*)&stg[px * 132 + cu * 8];
        *(bf16x8*)&g[((size_t)((b * 128 + y) * 128) + px) * 128 + cu * 8] = v;
    }
}

// ---------------------------------------------------------------------------
extern "C" void kernel_launch(void* const* d_in, const int* in_sizes, int n_in,
                              void* d_out, int out_size, void* d_ws, size_t ws_size,
                              hipStream_t stream)
{
    const float* x     = (const float*)d_in[0];
    const float* fc1_w = (const float*)d_in[1];
    const float* fc1_b = (const float*)d_in[2];
    const float* bn1_g = (const float*)d_in[3];
    const float* bn1_b = (const float*)d_in[4];
    const float* bn1_m = (const float*)d_in[5];
    const float* bn1_v = (const float*)d_in[6];
    const float* gc_w  = (const float*)d_in[7];
    const float* gc_b  = (const float*)d_in[8];
    const float* bng_g = (const float*)d_in[9];
    const float* bng_b = (const float*)d_in[10];
    const float* bng_m = (const float*)d_in[11];
    const float* bng_v = (const float*)d_in[12];
    const float* fc2_w = (const float*)d_in[13];
    const float* fc2_b = (const float*)d_in[14];
    const float* bn2_g = (const float*)d_in[15];
    const float* bn2_b = (const float*)d_in[16];
    const float* bn2_m = (const float*)d_in[17];
    const float* bn2_v = (const float*)d_in[18];

    char* wsb = (char*)d_ws;
    bf16* x_bf = (bf16*)wsb;                      // 33,554,432 B
    bf16* h    = (bf16*)(wsb + 33554432);         // 33,554,432 B
    bf16* g    = (bf16*)(wsb + 67108864);         // 67,108,864 B
    bf16* q    = (bf16*)(wsb + 134217728);        //  2,097,152 B
    bf16* o    = (bf16*)(wsb + 136314880);        //  2,097,152 B
    bf16* wt1  = (bf16*)(wsb + 138412032);        //     73,728 B
    bf16* wt2  = (bf16*)(wsb + 138485760);        //    147,456 B
    bf16* wtg  = (bf16*)(wsb + 138633216);        //     32,768 B
    bf16* zb   = (bf16*)(wsb + 138665984);        //      1,024 B

    prep_conv_w<64><<<16, 256, 0, stream>>>(fc1_w, wt1);
    prep_conv_w<128><<<32, 256, 0, stream>>>(fc2_w, wt2);
    prep_1x1_w<<<64, 256, 0, stream>>>(gc_w, wtg);

    cvt_x_nhwc<<<dim3(256, 16), 256, 0, stream>>>(x, x_bf, (float*)zb);

    conv3x3_mfma<64, 0><<<512, 512, 0, stream>>>(
        x_bf, wt1, fc1_b, bn1_g, bn1_b, bn1_m, bn1_v, nullptr, zb, h);

    gather_q<<<512, 256, 0, stream>>>(h, q);

    attn_fused<<<dim3(16, 16), 256, 0, stream>>>(q, o);

    conv1x1_mfma<<<dim3(128, 16), 256, 0, stream>>>(
        h, o, wtg, gc_b, bng_g, bng_b, bng_m, bng_v, g);

    conv3x3_mfma<128, 1><<<512, 512, 0, stream>>>(
        g, wt2, fc2_b, bn2_g, bn2_b, bn2_m, bn2_v, x_bf, zb, (float*)d_out);
}